// Round 1
// baseline (243.433 us; speedup 1.0000x reference)
//
#include <hip/hip_runtime.h>

#define NB 4
#define NCI 64
#define NCO 64
#define NH 256
#define NW 256
#define NIMG (NB*NCI)      // 256
#define PLANE (NIMG*NH)    // 65536

// workspace offsets (in floats)
#define OF_COS 0
#define OF_SIN 256
#define OF_TW  512                      // [30][256] final-stage trig (ky=1..15 cos/sin)
#define OF_TK1 8192                     // [256][32] stage-1 trig
#define OF_XW  16384                    // 32 planes x PLANE (re ky0..15, im ky0..15); reused as S
#define OF_S   OF_XW
#define OF_XS_RE (OF_XW + 32*PLANE)
#define OF_XS_IM (OF_XS_RE + PLANE)
#define OF_O1_RE (OF_XS_IM + PLANE)
#define OF_O1_IM (OF_O1_RE + PLANE)
#define OF_O2_RE (OF_O1_IM + PLANE)
#define OF_O2_IM (OF_O2_RE + PLANE)

__global__ __launch_bounds__(256) void k0_init(float* __restrict__ ws) {
  const int t = threadIdx.x;
  const double TP = 6.283185307179586;
  {
    double a = TP * t / 256.0;
    ws[OF_COS + t] = (float)cos(a);
    ws[OF_SIN + t] = (float)sin(a);
  }
  for (int idx = t; idx < 30*256; idx += 256) {
    int p = idx >> 8, w = idx & 255;
    int ky = (p >> 1) + 1;
    double a = TP * ((ky * w) & 255) / 256.0;
    ws[OF_TW + idx] = (p & 1) ? (float)sin(a) : (float)cos(a);
  }
  for (int idx = t; idx < 256*32; idx += 256) {
    int w = idx >> 5, o = idx & 31;
    double v;
    if (o < 16) v =  cos(TP * ((o * w) & 255) / 256.0);
    else        v = -sin(TP * (((o - 16) * w) & 255) / 256.0);
    ws[OF_TK1 + idx] = (float)v;
  }
}

// Stage 1: Xw[plane][img*256+h] ; plane<16: Re(ky) ; plane>=16: Im(ky-16)
__global__ __launch_bounds__(256) void k1_dftw(const float* __restrict__ x,
                                               float* __restrict__ ws) {
  __shared__ float trig[256*32];   // [w][o]
  __shared__ float xls[16*128];    // [w_chunk][row_local]
  const int t = threadIdx.x;
  const int img = blockIdx.x >> 1;
  const int row0 = (blockIdx.x & 1) * 128;

  for (int idx = t; idx < 256*32; idx += 256)
    trig[idx] = ws[OF_TK1 + idx];

  const int to = t & 3, tr = t >> 2;     // tr 0..63
  float acc[2][8];
#pragma unroll
  for (int r = 0; r < 2; ++r)
#pragma unroll
    for (int o = 0; o < 8; ++o) acc[r][o] = 0.f;

  const float* xbase = x + (size_t)img * (NH*NW) + row0 * NW;
  const int lrow = t >> 1, half = t & 1;

  for (int cch = 0; cch < 16; ++cch) {
    const int w0 = cch * 16;
    __syncthreads();
    float4 v0 = *(const float4*)(xbase + lrow*NW + w0 + half*8);
    float4 v1 = *(const float4*)(xbase + lrow*NW + w0 + half*8 + 4);
    const int wb = half * 8;
    xls[(wb+0)*128 + lrow] = v0.x;
    xls[(wb+1)*128 + lrow] = v0.y;
    xls[(wb+2)*128 + lrow] = v0.z;
    xls[(wb+3)*128 + lrow] = v0.w;
    xls[(wb+4)*128 + lrow] = v1.x;
    xls[(wb+5)*128 + lrow] = v1.y;
    xls[(wb+6)*128 + lrow] = v1.z;
    xls[(wb+7)*128 + lrow] = v1.w;
    __syncthreads();
#pragma unroll 4
    for (int w = 0; w < 16; ++w) {
      const float2 xv = *(const float2*)&xls[w*128 + tr*2];
      const float4 t0 = *(const float4*)&trig[(w0+w)*32 + to*8];
      const float4 t1 = *(const float4*)&trig[(w0+w)*32 + to*8 + 4];
      acc[0][0] += xv.x * t0.x;  acc[1][0] += xv.y * t0.x;
      acc[0][1] += xv.x * t0.y;  acc[1][1] += xv.y * t0.y;
      acc[0][2] += xv.x * t0.z;  acc[1][2] += xv.y * t0.z;
      acc[0][3] += xv.x * t0.w;  acc[1][3] += xv.y * t0.w;
      acc[0][4] += xv.x * t1.x;  acc[1][4] += xv.y * t1.x;
      acc[0][5] += xv.x * t1.y;  acc[1][5] += xv.y * t1.y;
      acc[0][6] += xv.x * t1.z;  acc[1][6] += xv.y * t1.z;
      acc[0][7] += xv.x * t1.w;  acc[1][7] += xv.y * t1.w;
    }
  }
  float* Xw = ws + OF_XW;
  const int rowg = row0 + tr*2;
#pragma unroll
  for (int o = 0; o < 8; ++o) {
    const int plane = to*8 + o;
    float2 st; st.x = acc[0][o]; st.y = acc[1][o];
    *(float2*)&Xw[(size_t)plane*PLANE + img*NH + rowg] = st;
  }
}

// Stage 2: xs[img][kx*16+ky] = sum_h Xw[h][ky] * e^{-2pi i kx h/256}
__global__ __launch_bounds__(256) void k2_dfth(float* __restrict__ ws) {
  __shared__ float L[32*257];   // [plane][h], pad 257
  const int t = threadIdx.x, img = blockIdx.x;
  const float* Xw = ws + OF_XW;
  for (int p = 0; p < 32; ++p)
    L[p*257 + t] = Xw[(size_t)p*PLANE + img*256 + t];
  __syncthreads();
  const int kx = t >> 4, ky = t & 15;
  const float cd = ws[OF_COS + kx];
  const float sd = ws[OF_SIN + kx];
  float c = 1.f, s = 0.f, ar = 0.f, ai = 0.f;
#pragma unroll 4
  for (int h = 0; h < 256; ++h) {
    const float xr = L[ky*257 + h];
    const float xi = L[(16+ky)*257 + h];
    ar += xr*c + xi*s;
    ai += xi*c - xr*s;
    const float nc = c*cd - s*sd;
    const float ns = s*cd + c*sd;
    c = nc; s = ns;
  }
  ws[OF_XS_RE + img*256 + t] = ar;
  ws[OF_XS_IM + img*256 + t] = ai;
}

// Stage 3: o1/o2[b,o,m] = sum_i xs[b,i,m] * (wr + i wi)[i,o,m]   (einsum binds w axis0 to i)
__global__ __launch_bounds__(1024) void k3_mix(const float* __restrict__ w1r,
    const float* __restrict__ w1i, const float* __restrict__ w2r,
    const float* __restrict__ w2i, float* __restrict__ ws) {
  const int o = blockIdx.x;      // 0..63
  const int t = threadIdx.x;     // 1024
  const int m = t & 255, b = t >> 8;
  const float* xsr = ws + OF_XS_RE;
  const float* xsi = ws + OF_XS_IM;
  float a1r=0.f, a1i=0.f, a2r=0.f, a2i=0.f;
#pragma unroll 4
  for (int i = 0; i < NCI; ++i) {
    const float xr = xsr[((b*NCI + i) << 8) + m];
    const float xi = xsi[((b*NCI + i) << 8) + m];
    const int wi = ((i*NCO + o) << 8) + m;
    const float p = w1r[wi], q = w1i[wi], u = w2r[wi], v = w2i[wi];
    a1r += xr*p - xi*q;
    a1i += xr*q + xi*p;
    a2r += xr*u - xi*v;
    a2i += xr*v + xi*u;
  }
  const int oi = ((b*NCO + o) << 8) + m;
  ws[OF_O1_RE + oi] = a1r;
  ws[OF_O1_IM + oi] = a1i;
  ws[OF_O2_RE + oi] = a2r;
  ws[OF_O2_IM + oi] = a2i;
}

// Stage 4: S[b,o,h,ky] = sum_j o1[j,ky] e^{+2pi i j h/256} + o2[j,ky] e^{+2pi i (j-16) h/256}
// stored as ky-planes: S[ky][bo*256+h] (re), S[16+ky][...] (im)
__global__ __launch_bounds__(256) void k4_idfth(float* __restrict__ ws) {
  __shared__ float o1r[256], o1i[256], o2r[256], o2i[256], cst[256], snt[256];
  const int t = threadIdx.x;
  const int bo = blockIdx.x;     // b*64+o
  o1r[t] = ws[OF_O1_RE + bo*256 + t];
  o1i[t] = ws[OF_O1_IM + bo*256 + t];
  o2r[t] = ws[OF_O2_RE + bo*256 + t];
  o2i[t] = ws[OF_O2_IM + bo*256 + t];
  cst[t] = ws[OF_COS + t];
  snt[t] = ws[OF_SIN + t];
  __syncthreads();
  const int h = t;
  float sr[16], si[16];
#pragma unroll
  for (int k = 0; k < 16; ++k) { sr[k] = 0.f; si[k] = 0.f; }
  for (int j = 0; j < 16; ++j) {
    const int m1 = (j*h) & 255;
    const int m2 = ((j+240)*h) & 255;   // (j-16)h mod 256
    const float c1 = cst[m1], s1 = snt[m1];
    const float c2 = cst[m2], s2 = snt[m2];
#pragma unroll
    for (int ky = 0; ky < 16; ++ky) {
      const float r1 = o1r[j*16+ky], i1 = o1i[j*16+ky];
      const float r2 = o2r[j*16+ky], i2 = o2i[j*16+ky];
      sr[ky] += r1*c1 - i1*s1 + r2*c2 - i2*s2;
      si[ky] += r1*s1 + i1*c1 + r2*s2 + i2*c2;
    }
  }
  float* S = ws + OF_S;
#pragma unroll
  for (int ky = 0; ky < 16; ++ky) {
    S[(size_t)ky*PLANE + bo*256 + h]      = sr[ky];
    S[(size_t)(16+ky)*PLANE + bo*256 + h] = si[ky];
  }
}

// Stage 5: out[row][w] = (ReS0 + 2*sum_{ky=1..15} ReS*cos - ImS*sin) / 65536
__global__ __launch_bounds__(256) void k5_idftw(const float* __restrict__ ws,
                                                float* __restrict__ out) {
  const int t = threadIdx.x;          // w
  const int bo = blockIdx.x >> 4;
  const int h0 = (blockIdx.x & 15) << 4;
  const float* Tw = ws + OF_TW;
  float c[15], s[15];
#pragma unroll
  for (int k = 0; k < 15; ++k) {
    c[k] = Tw[(2*k)*256 + t];
    s[k] = Tw[(2*k+1)*256 + t];
  }
  const float* S = ws + OF_S;
  const float scale = 2.0f / 65536.0f;
  for (int hh = 0; hh < 16; ++hh) {
    const int row = bo*256 + h0 + hh;
    float acc = 0.5f * S[row];                      // Re S(ky=0); Im ignored (c2r)
#pragma unroll
    for (int k = 0; k < 15; ++k) {
      acc += S[(size_t)(k+1)*PLANE + row] * c[k];
      acc -= S[(size_t)(17+k)*PLANE + row] * s[k];
    }
    out[(size_t)row*256 + t] = acc * scale;
  }
}

extern "C" void kernel_launch(void* const* d_in, const int* in_sizes, int n_in,
                              void* d_out, int out_size, void* d_ws, size_t ws_size,
                              hipStream_t stream) {
  const float* x   = (const float*)d_in[0];
  const float* w1r = (const float*)d_in[1];
  const float* w1i = (const float*)d_in[2];
  const float* w2r = (const float*)d_in[3];
  const float* w2i = (const float*)d_in[4];
  float* out = (float*)d_out;
  float* ws  = (float*)d_ws;

  hipLaunchKernelGGL(k0_init, dim3(1),    dim3(256),  0, stream, ws);
  hipLaunchKernelGGL(k1_dftw, dim3(512),  dim3(256),  0, stream, x, ws);
  hipLaunchKernelGGL(k2_dfth, dim3(256),  dim3(256),  0, stream, ws);
  hipLaunchKernelGGL(k3_mix,  dim3(64),   dim3(1024), 0, stream, w1r, w1i, w2r, w2i, ws);
  hipLaunchKernelGGL(k4_idfth,dim3(256),  dim3(256),  0, stream, ws);
  hipLaunchKernelGGL(k5_idftw,dim3(4096), dim3(256),  0, stream, ws, out);
}

// Round 2
// 119.199 us; speedup vs baseline: 2.0422x; 2.0422x over previous
//
#include <hip/hip_runtime.h>

#define NB 4
#define NCI 64
#define NCO 64
#define NH 256
#define NW 256
#define NIMG (NB*NCI)      // 256
#define PLANE (NIMG*NH)    // 65536

// workspace offsets (in floats)
#define OF_COS 0
#define OF_SIN 256
#define OF_TW  512                      // [30][256] final-stage trig (ky=1..15 cos/sin)
#define OF_TK1 8192                     // [256][32] stage-1 trig
#define OF_XW  16384                    // 32 planes x PLANE (re ky0..15, im ky0..15); reused as S2
#define OF_S   OF_XW                    // reused: S2 row-major [65536][32]
#define OF_XS_RE (OF_XW + 32*PLANE)
#define OF_XS_IM (OF_XS_RE + PLANE)
#define OF_O1_RE (OF_XS_IM + PLANE)
#define OF_O1_IM (OF_O1_RE + PLANE)
#define OF_O2_RE (OF_O1_IM + PLANE)
#define OF_O2_IM (OF_O2_RE + PLANE)

__global__ __launch_bounds__(256) void k0_init(float* __restrict__ ws) {
  const int t = threadIdx.x;
  const double TP = 6.283185307179586;
  {
    double a = TP * t / 256.0;
    ws[OF_COS + t] = (float)cos(a);
    ws[OF_SIN + t] = (float)sin(a);
  }
  for (int idx = t; idx < 30*256; idx += 256) {
    int p = idx >> 8, w = idx & 255;
    int ky = (p >> 1) + 1;
    double a = TP * ((ky * w) & 255) / 256.0;
    ws[OF_TW + idx] = (p & 1) ? (float)sin(a) : (float)cos(a);
  }
  for (int idx = t; idx < 256*32; idx += 256) {
    int w = idx >> 5, o = idx & 31;
    double v;
    if (o < 16) v =  cos(TP * ((o * w) & 255) / 256.0);
    else        v = -sin(TP * (((o - 16) * w) & 255) / 256.0);
    ws[OF_TK1 + idx] = (float)v;
  }
}

// Stage 1: Xw[plane][img*256+h] ; plane<16: Re(ky) ; plane>=16: Im(ky-16)
__global__ __launch_bounds__(256) void k1_dftw(const float* __restrict__ x,
                                               float* __restrict__ ws) {
  __shared__ float trig[256*32];   // [w][o]
  __shared__ float xls[16*128];    // [w_chunk][row_local]
  const int t = threadIdx.x;
  const int img = blockIdx.x >> 1;
  const int row0 = (blockIdx.x & 1) * 128;

  for (int idx = t; idx < 256*32; idx += 256)
    trig[idx] = ws[OF_TK1 + idx];

  const int to = t & 3, tr = t >> 2;     // tr 0..63
  float acc[2][8];
#pragma unroll
  for (int r = 0; r < 2; ++r)
#pragma unroll
    for (int o = 0; o < 8; ++o) acc[r][o] = 0.f;

  const float* xbase = x + (size_t)img * (NH*NW) + row0 * NW;
  const int lrow = t >> 1, half = t & 1;

  for (int cch = 0; cch < 16; ++cch) {
    const int w0 = cch * 16;
    __syncthreads();
    float4 v0 = *(const float4*)(xbase + lrow*NW + w0 + half*8);
    float4 v1 = *(const float4*)(xbase + lrow*NW + w0 + half*8 + 4);
    const int wb = half * 8;
    xls[(wb+0)*128 + lrow] = v0.x;
    xls[(wb+1)*128 + lrow] = v0.y;
    xls[(wb+2)*128 + lrow] = v0.z;
    xls[(wb+3)*128 + lrow] = v0.w;
    xls[(wb+4)*128 + lrow] = v1.x;
    xls[(wb+5)*128 + lrow] = v1.y;
    xls[(wb+6)*128 + lrow] = v1.z;
    xls[(wb+7)*128 + lrow] = v1.w;
    __syncthreads();
#pragma unroll 4
    for (int w = 0; w < 16; ++w) {
      const float2 xv = *(const float2*)&xls[w*128 + tr*2];
      const float4 t0 = *(const float4*)&trig[(w0+w)*32 + to*8];
      const float4 t1 = *(const float4*)&trig[(w0+w)*32 + to*8 + 4];
      acc[0][0] += xv.x * t0.x;  acc[1][0] += xv.y * t0.x;
      acc[0][1] += xv.x * t0.y;  acc[1][1] += xv.y * t0.y;
      acc[0][2] += xv.x * t0.z;  acc[1][2] += xv.y * t0.z;
      acc[0][3] += xv.x * t0.w;  acc[1][3] += xv.y * t0.w;
      acc[0][4] += xv.x * t1.x;  acc[1][4] += xv.y * t1.x;
      acc[0][5] += xv.x * t1.y;  acc[1][5] += xv.y * t1.y;
      acc[0][6] += xv.x * t1.z;  acc[1][6] += xv.y * t1.z;
      acc[0][7] += xv.x * t1.w;  acc[1][7] += xv.y * t1.w;
    }
  }
  float* Xw = ws + OF_XW;
  const int rowg = row0 + tr*2;
#pragma unroll
  for (int o = 0; o < 8; ++o) {
    const int plane = to*8 + o;
    float2 st; st.x = acc[0][o]; st.y = acc[1][o];
    *(float2*)&Xw[(size_t)plane*PLANE + img*NH + rowg] = st;
  }
}

// Stage 2: xs[img][kx*16+ky] = sum_h Xw[h][ky] * e^{-2pi i kx h/256}
__global__ __launch_bounds__(256) void k2_dfth(float* __restrict__ ws) {
  __shared__ float L[32*257];   // [plane][h], pad 257
  const int t = threadIdx.x, img = blockIdx.x;
  const float* Xw = ws + OF_XW;
  for (int p = 0; p < 32; ++p)
    L[p*257 + t] = Xw[(size_t)p*PLANE + img*256 + t];
  __syncthreads();
  const int kx = t >> 4, ky = t & 15;
  const float cd = ws[OF_COS + kx];
  const float sd = ws[OF_SIN + kx];
  float c = 1.f, s = 0.f, ar = 0.f, ai = 0.f;
#pragma unroll 4
  for (int h = 0; h < 256; ++h) {
    const float xr = L[ky*257 + h];
    const float xi = L[(16+ky)*257 + h];
    ar += xr*c + xi*s;
    ai += xi*c - xr*s;
    const float nc = c*cd - s*sd;
    const float ns = s*cd + c*sd;
    c = nc; s = ns;
  }
  ws[OF_XS_RE + img*256 + t] = ar;
  ws[OF_XS_IM + img*256 + t] = ai;
}

// Stage 3: o1/o2[b,o,m] = sum_i xs[b,i,m] * (wr + i wi)[i,o,m]   (einsum binds w axis0 to i)
// grid (64 o, 4 mode-chunks), 256 threads: b = t>>6, m = mc*64 + (t&63)
__global__ __launch_bounds__(256) void k3_mix(const float* __restrict__ w1r,
    const float* __restrict__ w1i, const float* __restrict__ w2r,
    const float* __restrict__ w2i, float* __restrict__ ws) {
  const int o  = blockIdx.x;     // 0..63
  const int mc = blockIdx.y;     // 0..3
  const int t  = threadIdx.x;    // 256
  const int b  = t >> 6;
  const int m  = (mc << 6) + (t & 63);
  const float* xsr = ws + OF_XS_RE;
  const float* xsi = ws + OF_XS_IM;
  float a1r=0.f, a1i=0.f, a2r=0.f, a2i=0.f;
#pragma unroll 4
  for (int i = 0; i < NCI; ++i) {
    const float xr = xsr[((b*NCI + i) << 8) + m];
    const float xi = xsi[((b*NCI + i) << 8) + m];
    const int wi = ((i*NCO + o) << 8) + m;
    const float p = w1r[wi], q = w1i[wi], u = w2r[wi], v = w2i[wi];
    a1r += xr*p - xi*q;
    a1i += xr*q + xi*p;
    a2r += xr*u - xi*v;
    a2i += xr*v + xi*u;
  }
  const int oi = ((b*NCO + o) << 8) + m;
  ws[OF_O1_RE + oi] = a1r;
  ws[OF_O1_IM + oi] = a1i;
  ws[OF_O2_RE + oi] = a2r;
  ws[OF_O2_IM + oi] = a2i;
}

// Stage 4: S[b,o,h,ky] = sum_j o1[j,ky] e^{+2pi i j h/256} + o2[j,ky] e^{+2pi i (j-16) h/256}
// NEW layout: S2 row-major [row = bo*256+h][32]  (cols 0..15 = Re ky, 16..31 = Im ky)
__global__ __launch_bounds__(256) void k4_idfth(float* __restrict__ ws) {
  __shared__ float o1r[256], o1i[256], o2r[256], o2i[256], cst[256], snt[256];
  __shared__ float st[256*33];   // [h][k] padded
  const int t = threadIdx.x;
  const int bo = blockIdx.x;     // b*64+o
  o1r[t] = ws[OF_O1_RE + bo*256 + t];
  o1i[t] = ws[OF_O1_IM + bo*256 + t];
  o2r[t] = ws[OF_O2_RE + bo*256 + t];
  o2i[t] = ws[OF_O2_IM + bo*256 + t];
  cst[t] = ws[OF_COS + t];
  snt[t] = ws[OF_SIN + t];
  __syncthreads();
  const int h = t;
  float sr[16], si[16];
#pragma unroll
  for (int k = 0; k < 16; ++k) { sr[k] = 0.f; si[k] = 0.f; }
  for (int j = 0; j < 16; ++j) {
    const int m1 = (j*h) & 255;
    const int m2 = ((j+240)*h) & 255;   // (j-16)h mod 256
    const float c1 = cst[m1], s1 = snt[m1];
    const float c2 = cst[m2], s2 = snt[m2];
#pragma unroll
    for (int ky = 0; ky < 16; ++ky) {
      const float r1 = o1r[j*16+ky], i1 = o1i[j*16+ky];
      const float r2 = o2r[j*16+ky], i2 = o2i[j*16+ky];
      sr[ky] += r1*c1 - i1*s1 + r2*c2 - i2*s2;
      si[ky] += r1*s1 + i1*c1 + r2*s2 + i2*c2;
    }
  }
#pragma unroll
  for (int k = 0; k < 16; ++k) {
    st[t*33 + k]      = sr[k];
    st[t*33 + 16 + k] = si[k];
  }
  __syncthreads();
  float* S2 = ws + OF_S;
  const size_t base = (size_t)bo * 8192;
#pragma unroll
  for (int i = t; i < 8192; i += 256)
    S2[base + i] = st[(i >> 5)*33 + (i & 31)];
}

// Stage 5: out[row][w] = (S0 + 2*sum_{ky=1..15} ReS*cos - ImS*sin) / 65536
// S2 row-major: per-row 32 contiguous floats, uniform address -> scalar loads.
__global__ __launch_bounds__(256) void k5_idftw(const float* __restrict__ ws,
                                                float* __restrict__ out) {
  const int t = threadIdx.x;          // w
  const int row0 = blockIdx.x << 6;   // 64 rows per block, grid 1024
  const float* Tw = ws + OF_TW;
  float c[15], s[15];
#pragma unroll
  for (int k = 0; k < 15; ++k) {
    c[k] = Tw[(2*k)*256 + t];
    s[k] = Tw[(2*k+1)*256 + t];
  }
  const float* S2 = ws + OF_S;
  const float scale = 2.0f / 65536.0f;
#pragma unroll 2
  for (int rr = 0; rr < 64; ++rr) {
    const int row = row0 + rr;
    const float* Srow = S2 + (size_t)row * 32;
    float acc = 0.5f * Srow[0];
#pragma unroll
    for (int k = 0; k < 15; ++k) {
      acc += Srow[1 + k]  * c[k];
      acc -= Srow[17 + k] * s[k];
    }
    out[(size_t)row * 256 + t] = acc * scale;
  }
}

extern "C" void kernel_launch(void* const* d_in, const int* in_sizes, int n_in,
                              void* d_out, int out_size, void* d_ws, size_t ws_size,
                              hipStream_t stream) {
  const float* x   = (const float*)d_in[0];
  const float* w1r = (const float*)d_in[1];
  const float* w1i = (const float*)d_in[2];
  const float* w2r = (const float*)d_in[3];
  const float* w2i = (const float*)d_in[4];
  float* out = (float*)d_out;
  float* ws  = (float*)d_ws;

  hipLaunchKernelGGL(k0_init, dim3(1),       dim3(256), 0, stream, ws);
  hipLaunchKernelGGL(k1_dftw, dim3(512),     dim3(256), 0, stream, x, ws);
  hipLaunchKernelGGL(k2_dfth, dim3(256),     dim3(256), 0, stream, ws);
  hipLaunchKernelGGL(k3_mix,  dim3(64, 4),   dim3(256), 0, stream, w1r, w1i, w2r, w2i, ws);
  hipLaunchKernelGGL(k4_idfth,dim3(256),     dim3(256), 0, stream, ws);
  hipLaunchKernelGGL(k5_idftw,dim3(1024),    dim3(256), 0, stream, ws, out);
}

// Round 3
// 109.700 us; speedup vs baseline: 2.2191x; 1.0866x over previous
//
#include <hip/hip_runtime.h>

#define NB 4
#define NCI 64
#define NCO 64
#define NH 256
#define NW 256
#define NIMG (NB*NCI)      // 256
#define PLANE (NIMG*NH)    // 65536

// workspace offsets (in floats)
#define OF_COS 0
#define OF_SIN 256
#define OF_TW  512                      // [30][256] final-stage trig (ky=1..15 cos/sin)
#define OF_TK1 8192                     // [256][32] stage-1 trig
#define OF_XW  16384                    // 32 planes x PLANE (re ky0..15, im ky0..15)
#define OF_XS_RE (OF_XW + 32*PLANE)
#define OF_XS_IM (OF_XS_RE + PLANE)
#define OF_O1_RE (OF_XS_IM + PLANE)
#define OF_O1_IM (OF_O1_RE + PLANE)
#define OF_O2_RE (OF_O1_IM + PLANE)
#define OF_O2_IM (OF_O2_RE + PLANE)

__global__ __launch_bounds__(256) void k0_init(float* __restrict__ ws) {
  const int t = threadIdx.x;
  const double TP = 6.283185307179586;
  {
    double a = TP * t / 256.0;
    ws[OF_COS + t] = (float)cos(a);
    ws[OF_SIN + t] = (float)sin(a);
  }
  for (int idx = t; idx < 30*256; idx += 256) {
    int p = idx >> 8, w = idx & 255;
    int ky = (p >> 1) + 1;
    double a = TP * ((ky * w) & 255) / 256.0;
    ws[OF_TW + idx] = (p & 1) ? (float)sin(a) : (float)cos(a);
  }
  for (int idx = t; idx < 256*32; idx += 256) {
    int w = idx >> 5, o = idx & 31;
    double v;
    if (o < 16) v =  cos(TP * ((o * w) & 255) / 256.0);
    else        v = -sin(TP * (((o - 16) * w) & 255) / 256.0);
    ws[OF_TK1 + idx] = (float)v;
  }
}

// Stage 1: Xw[plane][img*256+h] ; plane<16: Re(ky) ; plane>=16: Im(ky-16)
__global__ __launch_bounds__(256) void k1_dftw(const float* __restrict__ x,
                                               float* __restrict__ ws) {
  __shared__ float trig[256*32];   // [w][o]
  __shared__ float xls[16*128];    // [w_chunk][row_local]
  const int t = threadIdx.x;
  const int img = blockIdx.x >> 1;
  const int row0 = (blockIdx.x & 1) * 128;

  for (int idx = t; idx < 256*32; idx += 256)
    trig[idx] = ws[OF_TK1 + idx];

  const int to = t & 3, tr = t >> 2;     // tr 0..63
  float acc[2][8];
#pragma unroll
  for (int r = 0; r < 2; ++r)
#pragma unroll
    for (int o = 0; o < 8; ++o) acc[r][o] = 0.f;

  const float* xbase = x + (size_t)img * (NH*NW) + row0 * NW;
  const int lrow = t >> 1, half = t & 1;

  for (int cch = 0; cch < 16; ++cch) {
    const int w0 = cch * 16;
    __syncthreads();
    float4 v0 = *(const float4*)(xbase + lrow*NW + w0 + half*8);
    float4 v1 = *(const float4*)(xbase + lrow*NW + w0 + half*8 + 4);
    const int wb = half * 8;
    xls[(wb+0)*128 + lrow] = v0.x;
    xls[(wb+1)*128 + lrow] = v0.y;
    xls[(wb+2)*128 + lrow] = v0.z;
    xls[(wb+3)*128 + lrow] = v0.w;
    xls[(wb+4)*128 + lrow] = v1.x;
    xls[(wb+5)*128 + lrow] = v1.y;
    xls[(wb+6)*128 + lrow] = v1.z;
    xls[(wb+7)*128 + lrow] = v1.w;
    __syncthreads();
#pragma unroll 4
    for (int w = 0; w < 16; ++w) {
      const float2 xv = *(const float2*)&xls[w*128 + tr*2];
      const float4 t0 = *(const float4*)&trig[(w0+w)*32 + to*8];
      const float4 t1 = *(const float4*)&trig[(w0+w)*32 + to*8 + 4];
      acc[0][0] += xv.x * t0.x;  acc[1][0] += xv.y * t0.x;
      acc[0][1] += xv.x * t0.y;  acc[1][1] += xv.y * t0.y;
      acc[0][2] += xv.x * t0.z;  acc[1][2] += xv.y * t0.z;
      acc[0][3] += xv.x * t0.w;  acc[1][3] += xv.y * t0.w;
      acc[0][4] += xv.x * t1.x;  acc[1][4] += xv.y * t1.x;
      acc[0][5] += xv.x * t1.y;  acc[1][5] += xv.y * t1.y;
      acc[0][6] += xv.x * t1.z;  acc[1][6] += xv.y * t1.z;
      acc[0][7] += xv.x * t1.w;  acc[1][7] += xv.y * t1.w;
    }
  }
  float* Xw = ws + OF_XW;
  const int rowg = row0 + tr*2;
#pragma unroll
  for (int o = 0; o < 8; ++o) {
    const int plane = to*8 + o;
    float2 st; st.x = acc[0][o]; st.y = acc[1][o];
    *(float2*)&Xw[(size_t)plane*PLANE + img*NH + rowg] = st;
  }
}

// Stage 2: xs[img][kx*16+ky] = sum_h Xw[h][ky] * e^{-2pi i kx h/256}
__global__ __launch_bounds__(256) void k2_dfth(float* __restrict__ ws) {
  __shared__ float L[32*257];   // [plane][h], pad 257
  const int t = threadIdx.x, img = blockIdx.x;
  const float* Xw = ws + OF_XW;
  for (int p = 0; p < 32; ++p)
    L[p*257 + t] = Xw[(size_t)p*PLANE + img*256 + t];
  __syncthreads();
  const int kx = t >> 4, ky = t & 15;
  const float cd = ws[OF_COS + kx];
  const float sd = ws[OF_SIN + kx];
  float c = 1.f, s = 0.f, ar = 0.f, ai = 0.f;
#pragma unroll 4
  for (int h = 0; h < 256; ++h) {
    const float xr = L[ky*257 + h];
    const float xi = L[(16+ky)*257 + h];
    ar += xr*c + xi*s;
    ai += xi*c - xr*s;
    const float nc = c*cd - s*sd;
    const float ns = s*cd + c*sd;
    c = nc; s = ns;
  }
  ws[OF_XS_RE + img*256 + t] = ar;
  ws[OF_XS_IM + img*256 + t] = ai;
}

// Stage 3: o1/o2[b,o,m] = sum_i xs[b,i,m] * (wr + i wi)[i,o,m]   (einsum binds w axis0 to i)
__global__ __launch_bounds__(256) void k3_mix(const float* __restrict__ w1r,
    const float* __restrict__ w1i, const float* __restrict__ w2r,
    const float* __restrict__ w2i, float* __restrict__ ws) {
  const int o  = blockIdx.x;     // 0..63
  const int mc = blockIdx.y;     // 0..3
  const int t  = threadIdx.x;    // 256
  const int b  = t >> 6;
  const int m  = (mc << 6) + (t & 63);
  const float* xsr = ws + OF_XS_RE;
  const float* xsi = ws + OF_XS_IM;
  float a1r=0.f, a1i=0.f, a2r=0.f, a2i=0.f;
#pragma unroll 4
  for (int i = 0; i < NCI; ++i) {
    const float xr = xsr[((b*NCI + i) << 8) + m];
    const float xi = xsi[((b*NCI + i) << 8) + m];
    const int wi = ((i*NCO + o) << 8) + m;
    const float p = w1r[wi], q = w1i[wi], u = w2r[wi], v = w2i[wi];
    a1r += xr*p - xi*q;
    a1i += xr*q + xi*p;
    a2r += xr*u - xi*v;
    a2i += xr*v + xi*u;
  }
  const int oi = ((b*NCO + o) << 8) + m;
  ws[OF_O1_RE + oi] = a1r;
  ws[OF_O1_IM + oi] = a1i;
  ws[OF_O2_RE + oi] = a2r;
  ws[OF_O2_IM + oi] = a2i;
}

// Fused stage 4+5: per block (bo, h-quarter of 64 rows):
//  phase A: S[hl][ky] (complex, 64x16) into LDS
//  phase B: out[row][w] = (S0 + 2*sum_{ky=1..15} ReS*cos - ImS*sin)/65536
__global__ __launch_bounds__(256) void k45_idft(const float* __restrict__ ws,
                                                float* __restrict__ out) {
  __shared__ __align__(16) float o1r[256], o1i[256], o2r[256], o2i[256];
  __shared__ float cst[256], snt[256];
  __shared__ __align__(16) float Sr[64][20], Si[64][20];  // pad 20 keeps rows 16B-aligned
  const int t  = threadIdx.x;
  const int bo = blockIdx.x >> 2;
  const int hc = blockIdx.x & 3;

  o1r[t] = ws[OF_O1_RE + bo*256 + t];
  o1i[t] = ws[OF_O1_IM + bo*256 + t];
  o2r[t] = ws[OF_O2_RE + bo*256 + t];
  o2i[t] = ws[OF_O2_IM + bo*256 + t];
  cst[t] = ws[OF_COS + t];
  snt[t] = ws[OF_SIN + t];

  // phase-B trig in registers (overlaps with LDS fill)
  const float* Tw = ws + OF_TW;
  float c[15], s[15];
#pragma unroll
  for (int k = 0; k < 15; ++k) {
    c[k] = Tw[(2*k)*256 + t];
    s[k] = Tw[(2*k+1)*256 + t];
  }
  __syncthreads();

  // ---- phase A: thread (hl, kq) computes S[hl][kq*4 .. kq*4+3] ----
  {
    const int hl = t >> 2, kq = t & 3;
    const int h  = hc*64 + hl;
    const int off = (240 * h) & 255;
    float4 sr = {0.f,0.f,0.f,0.f}, si = {0.f,0.f,0.f,0.f};
    int m1 = 0;
    for (int j = 0; j < 16; ++j) {
      const float c1 = cst[m1], s1 = snt[m1];
      const int m2 = (m1 + off) & 255;
      const float c2 = cst[m2], s2 = snt[m2];
      const float4 r1 = *(const float4*)&o1r[j*16 + kq*4];
      const float4 i1 = *(const float4*)&o1i[j*16 + kq*4];
      const float4 r2 = *(const float4*)&o2r[j*16 + kq*4];
      const float4 i2 = *(const float4*)&o2i[j*16 + kq*4];
      sr.x += r1.x*c1 - i1.x*s1 + r2.x*c2 - i2.x*s2;
      si.x += r1.x*s1 + i1.x*c1 + r2.x*s2 + i2.x*c2;
      sr.y += r1.y*c1 - i1.y*s1 + r2.y*c2 - i2.y*s2;
      si.y += r1.y*s1 + i1.y*c1 + r2.y*s2 + i2.y*c2;
      sr.z += r1.z*c1 - i1.z*s1 + r2.z*c2 - i2.z*s2;
      si.z += r1.z*s1 + i1.z*c1 + r2.z*s2 + i2.z*c2;
      sr.w += r1.w*c1 - i1.w*s1 + r2.w*c2 - i2.w*s2;
      si.w += r1.w*s1 + i1.w*c1 + r2.w*s2 + i2.w*c2;
      m1 = (m1 + h) & 255;
    }
    *(float4*)&Sr[hl][kq*4] = sr;
    *(float4*)&Si[hl][kq*4] = si;
  }
  __syncthreads();

  // ---- phase B: thread = w; loop 64 rows, S rows via LDS broadcast b128 ----
  const float scale = 2.0f / 65536.0f;
  const size_t outbase = ((size_t)bo*256 + hc*64) * 256 + t;
#pragma unroll 2
  for (int hl = 0; hl < 64; ++hl) {
    const float4 a0 = *(const float4*)&Sr[hl][0];
    const float4 a1 = *(const float4*)&Sr[hl][4];
    const float4 a2 = *(const float4*)&Sr[hl][8];
    const float4 a3 = *(const float4*)&Sr[hl][12];
    const float4 b0 = *(const float4*)&Si[hl][0];
    const float4 b1 = *(const float4*)&Si[hl][4];
    const float4 b2 = *(const float4*)&Si[hl][8];
    const float4 b3 = *(const float4*)&Si[hl][12];
    float acc = 0.5f * a0.x;
    acc += a0.y*c[0]  + a0.z*c[1]  + a0.w*c[2];
    acc += a1.x*c[3]  + a1.y*c[4]  + a1.z*c[5]  + a1.w*c[6];
    acc += a2.x*c[7]  + a2.y*c[8]  + a2.z*c[9]  + a2.w*c[10];
    acc += a3.x*c[11] + a3.y*c[12] + a3.z*c[13] + a3.w*c[14];
    acc -= b0.y*s[0]  + b0.z*s[1]  + b0.w*s[2];
    acc -= b1.x*s[3]  + b1.y*s[4]  + b1.z*s[5]  + b1.w*s[6];
    acc -= b2.x*s[7]  + b2.y*s[8]  + b2.z*s[9]  + b2.w*s[10];
    acc -= b3.x*s[11] + b3.y*s[12] + b3.z*s[13] + b3.w*s[14];
    out[outbase + (size_t)hl*256] = acc * scale;
  }
}

extern "C" void kernel_launch(void* const* d_in, const int* in_sizes, int n_in,
                              void* d_out, int out_size, void* d_ws, size_t ws_size,
                              hipStream_t stream) {
  const float* x   = (const float*)d_in[0];
  const float* w1r = (const float*)d_in[1];
  const float* w1i = (const float*)d_in[2];
  const float* w2r = (const float*)d_in[3];
  const float* w2i = (const float*)d_in[4];
  float* out = (float*)d_out;
  float* ws  = (float*)d_ws;

  hipLaunchKernelGGL(k0_init,  dim3(1),     dim3(256), 0, stream, ws);
  hipLaunchKernelGGL(k1_dftw,  dim3(512),   dim3(256), 0, stream, x, ws);
  hipLaunchKernelGGL(k2_dfth,  dim3(256),   dim3(256), 0, stream, ws);
  hipLaunchKernelGGL(k3_mix,   dim3(64, 4), dim3(256), 0, stream, w1r, w1i, w2r, w2i, ws);
  hipLaunchKernelGGL(k45_idft, dim3(1024),  dim3(256), 0, stream, ws, out);
}

// Round 4
// 97.539 us; speedup vs baseline: 2.4957x; 1.1247x over previous
//
#include <hip/hip_runtime.h>

#define NB 4
#define NCI 64
#define NCO 64
#define NH 256
#define NW 256
#define NIMG (NB*NCI)      // 256
#define PLANE (NIMG*NH)    // 65536

// workspace offsets (in floats)
#define OF_COS 0
#define OF_SIN 256
#define OF_TW  512                      // [30][256] final-stage trig (ky=1..15 cos/sin)
#define OF_TK1 8192                     // [256][32] stage-1 trig
#define OF_XW  16384                    // 32 planes x PLANE (re ky0..15, im ky0..15)
#define OF_XS_RE (OF_XW + 32*PLANE)
#define OF_XS_IM (OF_XS_RE + PLANE)
#define OF_O1_RE (OF_XS_IM + PLANE)
#define OF_O1_IM (OF_O1_RE + PLANE)
#define OF_O2_RE (OF_O1_IM + PLANE)
#define OF_O2_IM (OF_O2_RE + PLANE)

__global__ __launch_bounds__(256) void k0_init(float* __restrict__ ws) {
  const int t = threadIdx.x;
  const double TP = 6.283185307179586;
  {
    double a = TP * t / 256.0;
    ws[OF_COS + t] = (float)cos(a);
    ws[OF_SIN + t] = (float)sin(a);
  }
  for (int idx = t; idx < 30*256; idx += 256) {
    int p = idx >> 8, w = idx & 255;
    int ky = (p >> 1) + 1;
    double a = TP * ((ky * w) & 255) / 256.0;
    ws[OF_TW + idx] = (p & 1) ? (float)sin(a) : (float)cos(a);
  }
  for (int idx = t; idx < 256*32; idx += 256) {
    int w = idx >> 5, o = idx & 31;
    double v;
    if (o < 16) v =  cos(TP * ((o * w) & 255) / 256.0);
    else        v = -sin(TP * (((o - 16) * w) & 255) / 256.0);
    ws[OF_TK1 + idx] = (float)v;
  }
}

// Stage 1: Xw[plane][img*256+h] ; plane<16: Re(ky) ; plane>=16: Im(ky-16)
__global__ __launch_bounds__(256) void k1_dftw(const float* __restrict__ x,
                                               float* __restrict__ ws) {
  __shared__ float trig[256*32];   // [w][o]
  __shared__ float xls[16*128];    // [w_chunk][row_local]
  const int t = threadIdx.x;
  const int img = blockIdx.x >> 1;
  const int row0 = (blockIdx.x & 1) * 128;

  for (int idx = t; idx < 256*32; idx += 256)
    trig[idx] = ws[OF_TK1 + idx];

  const int to = t & 3, tr = t >> 2;     // tr 0..63
  float acc[2][8];
#pragma unroll
  for (int r = 0; r < 2; ++r)
#pragma unroll
    for (int o = 0; o < 8; ++o) acc[r][o] = 0.f;

  const float* xbase = x + (size_t)img * (NH*NW) + row0 * NW;
  const int lrow = t >> 1, half = t & 1;

  for (int cch = 0; cch < 16; ++cch) {
    const int w0 = cch * 16;
    __syncthreads();
    float4 v0 = *(const float4*)(xbase + lrow*NW + w0 + half*8);
    float4 v1 = *(const float4*)(xbase + lrow*NW + w0 + half*8 + 4);
    const int wb = half * 8;
    xls[(wb+0)*128 + lrow] = v0.x;
    xls[(wb+1)*128 + lrow] = v0.y;
    xls[(wb+2)*128 + lrow] = v0.z;
    xls[(wb+3)*128 + lrow] = v0.w;
    xls[(wb+4)*128 + lrow] = v1.x;
    xls[(wb+5)*128 + lrow] = v1.y;
    xls[(wb+6)*128 + lrow] = v1.z;
    xls[(wb+7)*128 + lrow] = v1.w;
    __syncthreads();
#pragma unroll 4
    for (int w = 0; w < 16; ++w) {
      const float2 xv = *(const float2*)&xls[w*128 + tr*2];
      const float4 t0 = *(const float4*)&trig[(w0+w)*32 + to*8];
      const float4 t1 = *(const float4*)&trig[(w0+w)*32 + to*8 + 4];
      acc[0][0] += xv.x * t0.x;  acc[1][0] += xv.y * t0.x;
      acc[0][1] += xv.x * t0.y;  acc[1][1] += xv.y * t0.y;
      acc[0][2] += xv.x * t0.z;  acc[1][2] += xv.y * t0.z;
      acc[0][3] += xv.x * t0.w;  acc[1][3] += xv.y * t0.w;
      acc[0][4] += xv.x * t1.x;  acc[1][4] += xv.y * t1.x;
      acc[0][5] += xv.x * t1.y;  acc[1][5] += xv.y * t1.y;
      acc[0][6] += xv.x * t1.z;  acc[1][6] += xv.y * t1.z;
      acc[0][7] += xv.x * t1.w;  acc[1][7] += xv.y * t1.w;
    }
  }
  float* Xw = ws + OF_XW;
  const int rowg = row0 + tr*2;
#pragma unroll
  for (int o = 0; o < 8; ++o) {
    const int plane = to*8 + o;
    float2 st; st.x = acc[0][o]; st.y = acc[1][o];
    *(float2*)&Xw[(size_t)plane*PLANE + img*NH + rowg] = st;
  }
}

// Stage 2: xs[img][kx*16+ky] = sum_h Xw[h][ky] * e^{-2pi i kx h/256}
__global__ __launch_bounds__(256) void k2_dfth(float* __restrict__ ws) {
  __shared__ float L[32*257];   // [plane][h], pad 257
  const int t = threadIdx.x, img = blockIdx.x;
  const float* Xw = ws + OF_XW;
  for (int p = 0; p < 32; ++p)
    L[p*257 + t] = Xw[(size_t)p*PLANE + img*256 + t];
  __syncthreads();
  const int kx = t >> 4, ky = t & 15;
  const float cd = ws[OF_COS + kx];
  const float sd = ws[OF_SIN + kx];
  float c = 1.f, s = 0.f, ar = 0.f, ai = 0.f;
#pragma unroll 4
  for (int h = 0; h < 256; ++h) {
    const float xr = L[ky*257 + h];
    const float xi = L[(16+ky)*257 + h];
    ar += xr*c + xi*s;
    ai += xi*c - xr*s;
    const float nc = c*cd - s*sd;
    const float ns = s*cd + c*sd;
    c = nc; s = ns;
  }
  ws[OF_XS_RE + img*256 + t] = ar;
  ws[OF_XS_IM + img*256 + t] = ai;
}

// Stage 3: o1/o2[b,o,m] = sum_i xs[b,i,m] * (wr + i wi)[i,o,m]   (einsum binds w axis0 to i)
__global__ __launch_bounds__(256) void k3_mix(const float* __restrict__ w1r,
    const float* __restrict__ w1i, const float* __restrict__ w2r,
    const float* __restrict__ w2i, float* __restrict__ ws) {
  const int o  = blockIdx.x;     // 0..63
  const int mc = blockIdx.y;     // 0..3
  const int t  = threadIdx.x;    // 256
  const int b  = t >> 6;
  const int m  = (mc << 6) + (t & 63);
  const float* xsr = ws + OF_XS_RE;
  const float* xsi = ws + OF_XS_IM;
  float a1r=0.f, a1i=0.f, a2r=0.f, a2i=0.f;
#pragma unroll 4
  for (int i = 0; i < NCI; ++i) {
    const float xr = xsr[((b*NCI + i) << 8) + m];
    const float xi = xsi[((b*NCI + i) << 8) + m];
    const int wi = ((i*NCO + o) << 8) + m;
    const float p = w1r[wi], q = w1i[wi], u = w2r[wi], v = w2i[wi];
    a1r += xr*p - xi*q;
    a1i += xr*q + xi*p;
    a2r += xr*u - xi*v;
    a2i += xr*v + xi*u;
  }
  const int oi = ((b*NCO + o) << 8) + m;
  ws[OF_O1_RE + oi] = a1r;
  ws[OF_O1_IM + oi] = a1i;
  ws[OF_O2_RE + oi] = a2r;
  ws[OF_O2_IM + oi] = a2i;
}

// Fused stage 4+5.
// phase A: S[hl][ky] (complex, 64x16) into LDS
// phase B: thread t -> row-group rg=t>>6 (16 rows), w0=t&63; computes
//          w in {w0, w0+64, w0+128, w0+192} reusing the same trig registers
//          (quarter-turn rotation is an exact swap/sign, compile-time).
__global__ __launch_bounds__(256) void k45_idft(const float* __restrict__ ws,
                                                float* __restrict__ out) {
  __shared__ __align__(16) float o1r[256], o1i[256], o2r[256], o2i[256];
  __shared__ float cst[256], snt[256];
  __shared__ __align__(16) float Sr[64][20], Si[64][20];  // pad 20 keeps rows 16B-aligned
  const int t  = threadIdx.x;
  const int bo = blockIdx.x >> 2;
  const int hc = blockIdx.x & 3;

  o1r[t] = ws[OF_O1_RE + bo*256 + t];
  o1i[t] = ws[OF_O1_IM + bo*256 + t];
  o2r[t] = ws[OF_O2_RE + bo*256 + t];
  o2i[t] = ws[OF_O2_IM + bo*256 + t];
  cst[t] = ws[OF_COS + t];
  snt[t] = ws[OF_SIN + t];

  // phase-B trig in registers (index by w0 only)
  const int w0 = t & 63;
  const float* Tw = ws + OF_TW;
  float c[15], s[15];
#pragma unroll
  for (int k = 0; k < 15; ++k) {
    c[k] = Tw[(2*k)*256 + w0];
    s[k] = Tw[(2*k+1)*256 + w0];
  }
  __syncthreads();

  // ---- phase A: thread (hl, kq) computes S[hl][kq*4 .. kq*4+3] ----
  {
    const int hl = t >> 2, kq = t & 3;
    const int h  = hc*64 + hl;
    const int off = (240 * h) & 255;
    float4 sr = {0.f,0.f,0.f,0.f}, si = {0.f,0.f,0.f,0.f};
    int m1 = 0;
    for (int j = 0; j < 16; ++j) {
      const float c1 = cst[m1], s1 = snt[m1];
      const int m2 = (m1 + off) & 255;
      const float c2 = cst[m2], s2 = snt[m2];
      const float4 r1 = *(const float4*)&o1r[j*16 + kq*4];
      const float4 i1 = *(const float4*)&o1i[j*16 + kq*4];
      const float4 r2 = *(const float4*)&o2r[j*16 + kq*4];
      const float4 i2 = *(const float4*)&o2i[j*16 + kq*4];
      sr.x += r1.x*c1 - i1.x*s1 + r2.x*c2 - i2.x*s2;
      si.x += r1.x*s1 + i1.x*c1 + r2.x*s2 + i2.x*c2;
      sr.y += r1.y*c1 - i1.y*s1 + r2.y*c2 - i2.y*s2;
      si.y += r1.y*s1 + i1.y*c1 + r2.y*s2 + i2.y*c2;
      sr.z += r1.z*c1 - i1.z*s1 + r2.z*c2 - i2.z*s2;
      si.z += r1.z*s1 + i1.z*c1 + r2.z*s2 + i2.z*c2;
      sr.w += r1.w*c1 - i1.w*s1 + r2.w*c2 - i2.w*s2;
      si.w += r1.w*s1 + i1.w*c1 + r2.w*s2 + i2.w*c2;
      m1 = (m1 + h) & 255;
    }
    *(float4*)&Sr[hl][kq*4] = sr;
    *(float4*)&Si[hl][kq*4] = si;
  }
  __syncthreads();

  // ---- phase B ----
  const int rg = t >> 6;               // 16-row group; uniform per wave
  const float scale = 2.0f / 65536.0f;
  const size_t rowbase = ((size_t)bo*256 + hc*64 + rg*16) * 256;
#pragma unroll 2
  for (int r = 0; r < 16; ++r) {
    const int hl = rg*16 + r;
    const float4 a0 = *(const float4*)&Sr[hl][0];
    const float4 a1 = *(const float4*)&Sr[hl][4];
    const float4 a2 = *(const float4*)&Sr[hl][8];
    const float4 a3 = *(const float4*)&Sr[hl][12];
    const float4 b0 = *(const float4*)&Si[hl][0];
    const float4 b1 = *(const float4*)&Si[hl][4];
    const float4 b2 = *(const float4*)&Si[hl][8];
    const float4 b3 = *(const float4*)&Si[hl][12];
    const float re[16] = {a0.x,a0.y,a0.z,a0.w, a1.x,a1.y,a1.z,a1.w,
                          a2.x,a2.y,a2.z,a2.w, a3.x,a3.y,a3.z,a3.w};
    const float im[16] = {b0.x,b0.y,b0.z,b0.w, b1.x,b1.y,b1.z,b1.w,
                          b2.x,b2.y,b2.z,b2.w, b3.x,b3.y,b3.z,b3.w};
    float acc[4];
#pragma unroll
    for (int q = 0; q < 4; ++q) acc[q] = 0.5f * re[0];
#pragma unroll
    for (int k = 0; k < 15; ++k) {
      const int ky = k + 1;
      const float R = re[ky], I = im[ky];
#pragma unroll
      for (int q = 0; q < 4; ++q) {
        const int rot = (ky * q) & 3;   // compile-time under full unroll
        if      (rot == 0) acc[q] += R*c[k] - I*s[k];
        else if (rot == 1) acc[q] -= R*s[k] + I*c[k];
        else if (rot == 2) acc[q] -= R*c[k] - I*s[k];
        else               acc[q] += R*s[k] + I*c[k];
      }
    }
    const size_t ob = rowbase + (size_t)r*256 + w0;
#pragma unroll
    for (int q = 0; q < 4; ++q)
      out[ob + q*64] = acc[q] * scale;
  }
}

extern "C" void kernel_launch(void* const* d_in, const int* in_sizes, int n_in,
                              void* d_out, int out_size, void* d_ws, size_t ws_size,
                              hipStream_t stream) {
  const float* x   = (const float*)d_in[0];
  const float* w1r = (const float*)d_in[1];
  const float* w1i = (const float*)d_in[2];
  const float* w2r = (const float*)d_in[3];
  const float* w2i = (const float*)d_in[4];
  float* out = (float*)d_out;
  float* ws  = (float*)d_ws;

  hipLaunchKernelGGL(k0_init,  dim3(1),     dim3(256), 0, stream, ws);
  hipLaunchKernelGGL(k1_dftw,  dim3(512),   dim3(256), 0, stream, x, ws);
  hipLaunchKernelGGL(k2_dfth,  dim3(256),   dim3(256), 0, stream, ws);
  hipLaunchKernelGGL(k3_mix,   dim3(64, 4), dim3(256), 0, stream, w1r, w1i, w2r, w2i, ws);
  hipLaunchKernelGGL(k45_idft, dim3(1024),  dim3(256), 0, stream, ws, out);
}

// Round 5
// 79.330 us; speedup vs baseline: 3.0686x; 1.2295x over previous
//
#include <hip/hip_runtime.h>

#define NB 4
#define NCI 64
#define NCO 64
#define NH 256
#define NW 256
#define NIMG (NB*NCI)      // 256
#define PLANE (NIMG*NH)    // 65536

// workspace offsets (in floats)
#define OF_COS 0
#define OF_SIN 256
#define OF_TW  512                      // [30][256] final-stage trig (ky=1..15 cos/sin)
#define OF_XW  16384                    // Xw: [img][32 cols][256 rows] = 2M floats
#define OF_XS_RE (OF_XW + 32*PLANE)
#define OF_XS_IM (OF_XS_RE + PLANE)
#define OF_O1_RE (OF_XS_IM + PLANE)
#define OF_O1_IM (OF_O1_RE + PLANE)
#define OF_O2_RE (OF_O1_IM + PLANE)
#define OF_O2_IM (OF_O2_RE + PLANE)

// grid 31: block 0 -> cos/sin tables; blocks 1..30 -> one TW row each
__global__ __launch_bounds__(256) void k0_init(float* __restrict__ ws) {
  const int t = threadIdx.x, b = blockIdx.x;
  const double TP = 6.283185307179586;
  if (b == 0) {
    double a = TP * t / 256.0;
    ws[OF_COS + t] = (float)cos(a);
    ws[OF_SIN + t] = (float)sin(a);
  } else {
    const int p = b - 1;              // 0..29
    const int ky = (p >> 1) + 1;
    double a = TP * ((ky * t) & 255) / 256.0;
    ws[OF_TW + p*256 + t] = (p & 1) ? (float)sin(a) : (float)cos(a);
  }
}

// Stage 1: w-DFT per row. One block per image. Rotation recurrence for trig,
// (w, w+128) folding halves FMAs. Xw out: [img][col][row], col<16: Re(ky),
// col>=16: Im(ky-16).
__global__ __launch_bounds__(256) void k1_dftw(const float* __restrict__ x,
                                               float* __restrict__ ws) {
  __shared__ float xT[64*260];         // [w-col 0..63][row 0..255], pad 260
  __shared__ float cst[256], snt[256];
  const int t = threadIdx.x;
  const int img = blockIdx.x;

  cst[t] = ws[OF_COS + t];
  snt[t] = ws[OF_SIN + t];

  const int l8 = t & 7, r5 = t >> 3;   // staging: 16B-slot, row-group
  const int g  = t & 3, tr = t >> 2;   // compute: ky-group, row-quad
  const int ky0 = g * 4;

  __syncthreads();

  float cd[4], sd[4];                  // per-ky rotation step e^{-2pi i ky/256}
#pragma unroll
  for (int kl = 0; kl < 4; ++kl) {
    cd[kl] = cst[ky0 + kl];
    sd[kl] = snt[ky0 + kl];
  }

  float ar[4][4], ai[4][4];            // [kl][row]
#pragma unroll
  for (int kl = 0; kl < 4; ++kl)
#pragma unroll
    for (int r = 0; r < 4; ++r) { ar[kl][r] = 0.f; ai[kl][r] = 0.f; }

  const float* xb = x + (size_t)img * 65536;
  float4 v[16];
  // prologue: load chunk 0 (cols 0..31 and 128..159)
#pragma unroll
  for (int jj = 0; jj < 8; ++jj) {
    const int row = r5 + 32*jj;
    v[jj]   = *(const float4*)(xb + row*256 + l8*4);
    v[8+jj] = *(const float4*)(xb + row*256 + 128 + l8*4);
  }

  for (int c = 0; c < 4; ++c) {
    __syncthreads();                   // previous chunk's readers done
#pragma unroll
    for (int jj = 0; jj < 8; ++jj) {
      const int row = r5 + 32*jj;
      xT[(l8*4+0)*260 + row] = v[jj].x;
      xT[(l8*4+1)*260 + row] = v[jj].y;
      xT[(l8*4+2)*260 + row] = v[jj].z;
      xT[(l8*4+3)*260 + row] = v[jj].w;
      xT[(32+l8*4+0)*260 + row] = v[8+jj].x;
      xT[(32+l8*4+1)*260 + row] = v[8+jj].y;
      xT[(32+l8*4+2)*260 + row] = v[8+jj].z;
      xT[(32+l8*4+3)*260 + row] = v[8+jj].w;
    }
    __syncthreads();
    if (c < 3) {                       // T14: issue next chunk loads now
      const int w0n = (c+1) * 32;
#pragma unroll
      for (int jj = 0; jj < 8; ++jj) {
        const int row = r5 + 32*jj;
        v[jj]   = *(const float4*)(xb + row*256 + w0n + l8*4);
        v[8+jj] = *(const float4*)(xb + row*256 + w0n + 128 + l8*4);
      }
    }
    // rotation init at w0 = c*32
    float cc[4], sv[4];
#pragma unroll
    for (int kl = 0; kl < 4; ++kl) {
      const int m = ((ky0 + kl) * c * 32) & 255;
      cc[kl] = cst[m];
      sv[kl] = snt[m];
    }
#pragma unroll 8
    for (int wl = 0; wl < 32; ++wl) {
      const float4 xlo = *(const float4*)&xT[wl*260 + tr*4];
      const float4 xhi = *(const float4*)&xT[(wl+32)*260 + tr*4];
      const float xe0 = xlo.x + xhi.x, xo0 = xlo.x - xhi.x;
      const float xe1 = xlo.y + xhi.y, xo1 = xlo.y - xhi.y;
      const float xe2 = xlo.z + xhi.z, xo2 = xlo.z - xhi.z;
      const float xe3 = xlo.w + xhi.w, xo3 = xlo.w - xhi.w;
#pragma unroll
      for (int kl = 0; kl < 4; ++kl) {
        const float s0 = (kl & 1) ? xo0 : xe0;
        const float s1 = (kl & 1) ? xo1 : xe1;
        const float s2 = (kl & 1) ? xo2 : xe2;
        const float s3 = (kl & 1) ? xo3 : xe3;
        ar[kl][0] += s0 * cc[kl];  ai[kl][0] -= s0 * sv[kl];
        ar[kl][1] += s1 * cc[kl];  ai[kl][1] -= s1 * sv[kl];
        ar[kl][2] += s2 * cc[kl];  ai[kl][2] -= s2 * sv[kl];
        ar[kl][3] += s3 * cc[kl];  ai[kl][3] -= s3 * sv[kl];
        const float nc = cc[kl]*cd[kl] - sv[kl]*sd[kl];
        const float ns = sv[kl]*cd[kl] + cc[kl]*sd[kl];
        cc[kl] = nc; sv[kl] = ns;
      }
    }
  }
  float* Xw = ws + OF_XW + (size_t)img * 8192;
#pragma unroll
  for (int kl = 0; kl < 4; ++kl) {
    const int ky = ky0 + kl;
    float4 sr; sr.x = ar[kl][0]; sr.y = ar[kl][1]; sr.z = ar[kl][2]; sr.w = ar[kl][3];
    float4 si; si.x = ai[kl][0]; si.y = ai[kl][1]; si.z = ai[kl][2]; si.w = ai[kl][3];
    *(float4*)&Xw[ky*256 + tr*4]      = sr;
    *(float4*)&Xw[(16+ky)*256 + tr*4] = si;
  }
}

// Stage 2: xs[img][kx*16+ky] = sum_h Xw[img][.][h] * e^{-2pi i kx h/256}
__global__ __launch_bounds__(256) void k2_dfth(float* __restrict__ ws) {
  __shared__ float L[32*257];   // [plane][h], pad 257
  const int t = threadIdx.x, img = blockIdx.x;
  const float* XwI = ws + OF_XW + (size_t)img * 8192;
  for (int p = 0; p < 32; ++p)
    L[p*257 + t] = XwI[p*256 + t];
  __syncthreads();
  const int kx = t >> 4, ky = t & 15;
  const float cdk = ws[OF_COS + kx];
  const float sdk = ws[OF_SIN + kx];
  float c = 1.f, s = 0.f, arr = 0.f, aii = 0.f;
#pragma unroll 4
  for (int h = 0; h < 256; ++h) {
    const float xr = L[ky*257 + h];
    const float xi = L[(16+ky)*257 + h];
    arr += xr*c + xi*s;
    aii += xi*c - xr*s;
    const float nc = c*cdk - s*sdk;
    const float ns = s*cdk + c*sdk;
    c = nc; s = ns;
  }
  ws[OF_XS_RE + img*256 + t] = arr;
  ws[OF_XS_IM + img*256 + t] = aii;
}

// Stage 3: o1/o2[b,o,m] = sum_i xs[b,i,m] * (wr + i wi)[i,o,m]
__global__ __launch_bounds__(256) void k3_mix(const float* __restrict__ w1r,
    const float* __restrict__ w1i, const float* __restrict__ w2r,
    const float* __restrict__ w2i, float* __restrict__ ws) {
  const int o  = blockIdx.x;     // 0..63
  const int mc = blockIdx.y;     // 0..3
  const int t  = threadIdx.x;    // 256
  const int b  = t >> 6;
  const int m  = (mc << 6) + (t & 63);
  const float* xsr = ws + OF_XS_RE;
  const float* xsi = ws + OF_XS_IM;
  float a1r=0.f, a1i=0.f, a2r=0.f, a2i=0.f;
#pragma unroll 4
  for (int i = 0; i < NCI; ++i) {
    const float xr = xsr[((b*NCI + i) << 8) + m];
    const float xi = xsi[((b*NCI + i) << 8) + m];
    const int wi = ((i*NCO + o) << 8) + m;
    const float p = w1r[wi], q = w1i[wi], u = w2r[wi], v = w2i[wi];
    a1r += xr*p - xi*q;
    a1i += xr*q + xi*p;
    a2r += xr*u - xi*v;
    a2i += xr*v + xi*u;
  }
  const int oi = ((b*NCO + o) << 8) + m;
  ws[OF_O1_RE + oi] = a1r;
  ws[OF_O1_IM + oi] = a1i;
  ws[OF_O2_RE + oi] = a2r;
  ws[OF_O2_IM + oi] = a2i;
}

// Fused stage 4+5.
// phase A: S[hl][ky] (complex, 64x16) into LDS; trig via dual rotation.
// phase B: thread t -> row-group rg=t>>6 (16 rows), w0=t&63; computes
//          w in {w0, w0+64, w0+128, w0+192} with quarter-turn swaps.
__global__ __launch_bounds__(256) void k45_idft(const float* __restrict__ ws,
                                                float* __restrict__ out) {
  __shared__ __align__(16) float o1r[256], o1i[256], o2r[256], o2i[256];
  __shared__ float cst[256], snt[256];
  __shared__ __align__(16) float Sr[64][20], Si[64][20];
  const int t  = threadIdx.x;
  const int bo = blockIdx.x >> 2;
  const int hc = blockIdx.x & 3;

  o1r[t] = ws[OF_O1_RE + bo*256 + t];
  o1i[t] = ws[OF_O1_IM + bo*256 + t];
  o2r[t] = ws[OF_O2_RE + bo*256 + t];
  o2i[t] = ws[OF_O2_IM + bo*256 + t];
  cst[t] = ws[OF_COS + t];
  snt[t] = ws[OF_SIN + t];

  const int w0 = t & 63;
  const float* Tw = ws + OF_TW;
  float c[15], s[15];
#pragma unroll
  for (int k = 0; k < 15; ++k) {
    c[k] = Tw[(2*k)*256 + w0];
    s[k] = Tw[(2*k+1)*256 + w0];
  }
  __syncthreads();

  // ---- phase A ----
  {
    const int hl = t >> 2, kq = t & 3;
    const int h  = hc*64 + hl;
    const float chh = cst[h], shh = snt[h];
    float c1 = 1.f, s1 = 0.f;
    const int m2i = (240 * h) & 255;
    float c2 = cst[m2i], s2 = snt[m2i];
    float4 sr = {0.f,0.f,0.f,0.f}, si = {0.f,0.f,0.f,0.f};
    for (int j = 0; j < 16; ++j) {
      const float4 r1 = *(const float4*)&o1r[j*16 + kq*4];
      const float4 i1 = *(const float4*)&o1i[j*16 + kq*4];
      const float4 r2 = *(const float4*)&o2r[j*16 + kq*4];
      const float4 i2 = *(const float4*)&o2i[j*16 + kq*4];
      sr.x += r1.x*c1 - i1.x*s1 + r2.x*c2 - i2.x*s2;
      si.x += r1.x*s1 + i1.x*c1 + r2.x*s2 + i2.x*c2;
      sr.y += r1.y*c1 - i1.y*s1 + r2.y*c2 - i2.y*s2;
      si.y += r1.y*s1 + i1.y*c1 + r2.y*s2 + i2.y*c2;
      sr.z += r1.z*c1 - i1.z*s1 + r2.z*c2 - i2.z*s2;
      si.z += r1.z*s1 + i1.z*c1 + r2.z*s2 + i2.z*c2;
      sr.w += r1.w*c1 - i1.w*s1 + r2.w*c2 - i2.w*s2;
      si.w += r1.w*s1 + i1.w*c1 + r2.w*s2 + i2.w*c2;
      const float n1c = c1*chh - s1*shh, n1s = s1*chh + c1*shh;
      const float n2c = c2*chh - s2*shh, n2s = s2*chh + c2*shh;
      c1 = n1c; s1 = n1s; c2 = n2c; s2 = n2s;
    }
    *(float4*)&Sr[hl][kq*4] = sr;
    *(float4*)&Si[hl][kq*4] = si;
  }
  __syncthreads();

  // ---- phase B ----
  const int rg = t >> 6;
  const float scale = 2.0f / 65536.0f;
  const size_t rowbase = ((size_t)bo*256 + hc*64 + rg*16) * 256;
#pragma unroll 2
  for (int r = 0; r < 16; ++r) {
    const int hl = rg*16 + r;
    const float4 a0 = *(const float4*)&Sr[hl][0];
    const float4 a1 = *(const float4*)&Sr[hl][4];
    const float4 a2 = *(const float4*)&Sr[hl][8];
    const float4 a3 = *(const float4*)&Sr[hl][12];
    const float4 b0 = *(const float4*)&Si[hl][0];
    const float4 b1 = *(const float4*)&Si[hl][4];
    const float4 b2 = *(const float4*)&Si[hl][8];
    const float4 b3 = *(const float4*)&Si[hl][12];
    const float re[16] = {a0.x,a0.y,a0.z,a0.w, a1.x,a1.y,a1.z,a1.w,
                          a2.x,a2.y,a2.z,a2.w, a3.x,a3.y,a3.z,a3.w};
    const float im[16] = {b0.x,b0.y,b0.z,b0.w, b1.x,b1.y,b1.z,b1.w,
                          b2.x,b2.y,b2.z,b2.w, b3.x,b3.y,b3.z,b3.w};
    float acc[4];
#pragma unroll
    for (int q = 0; q < 4; ++q) acc[q] = 0.5f * re[0];
#pragma unroll
    for (int k = 0; k < 15; ++k) {
      const int ky = k + 1;
      const float R = re[ky], I = im[ky];
#pragma unroll
      for (int q = 0; q < 4; ++q) {
        const int rot = (ky * q) & 3;
        if      (rot == 0) acc[q] += R*c[k] - I*s[k];
        else if (rot == 1) acc[q] -= R*s[k] + I*c[k];
        else if (rot == 2) acc[q] -= R*c[k] - I*s[k];
        else               acc[q] += R*s[k] + I*c[k];
      }
    }
    const size_t ob = rowbase + (size_t)r*256 + w0;
#pragma unroll
    for (int q = 0; q < 4; ++q)
      out[ob + q*64] = acc[q] * scale;
  }
}

extern "C" void kernel_launch(void* const* d_in, const int* in_sizes, int n_in,
                              void* d_out, int out_size, void* d_ws, size_t ws_size,
                              hipStream_t stream) {
  const float* x   = (const float*)d_in[0];
  const float* w1r = (const float*)d_in[1];
  const float* w1i = (const float*)d_in[2];
  const float* w2r = (const float*)d_in[3];
  const float* w2i = (const float*)d_in[4];
  float* out = (float*)d_out;
  float* ws  = (float*)d_ws;

  hipLaunchKernelGGL(k0_init,  dim3(31),    dim3(256), 0, stream, ws);
  hipLaunchKernelGGL(k1_dftw,  dim3(256),   dim3(256), 0, stream, x, ws);
  hipLaunchKernelGGL(k2_dfth,  dim3(256),   dim3(256), 0, stream, ws);
  hipLaunchKernelGGL(k3_mix,   dim3(64, 4), dim3(256), 0, stream, w1r, w1i, w2r, w2i, ws);
  hipLaunchKernelGGL(k45_idft, dim3(1024),  dim3(256), 0, stream, ws, out);
}

// Round 6
// 70.801 us; speedup vs baseline: 3.4383x; 1.1205x over previous
//
#include <hip/hip_runtime.h>

#define NB 4
#define NCI 64
#define NCO 64
#define NH 256
#define NW 256
#define NIMG (NB*NCI)      // 256
#define PLANE (NIMG*NH)    // 65536

// workspace offsets (in floats)
#define OF_COS 0
#define OF_SIN 256
#define OF_TW  512                      // [30][256] final-stage trig (ky=1..15 cos/sin)
#define OF_XS_RE (16384 + 32*PLANE)
#define OF_XS_IM (OF_XS_RE + PLANE)
#define OF_O1_RE (OF_XS_IM + PLANE)
#define OF_O1_IM (OF_O1_RE + PLANE)
#define OF_O2_RE (OF_O1_IM + PLANE)
#define OF_O2_IM (OF_O2_RE + PLANE)

// grid 31: block 0 -> cos/sin tables; blocks 1..30 -> one TW row each
__global__ __launch_bounds__(256) void k0_init(float* __restrict__ ws) {
  const int t = threadIdx.x, b = blockIdx.x;
  const double TP = 6.283185307179586;
  if (b == 0) {
    double a = TP * t / 256.0;
    ws[OF_COS + t] = (float)cos(a);
    ws[OF_SIN + t] = (float)sin(a);
  } else {
    const int p = b - 1;              // 0..29
    const int ky = (p >> 1) + 1;
    double a = TP * ((ky * t) & 255) / 256.0;
    ws[OF_TW + p*256 + t] = (p & 1) ? (float)sin(a) : (float)cos(a);
  }
}

// Fused stage 1+2: per image block.
// part 1: w-DFT per row with (w,w+128) folding + rotation recurrence -> L2 LDS
// part 2: h-DFT over L2 -> xs (global)
__global__ __launch_bounds__(256) void k12_dft(const float* __restrict__ x,
                                               float* __restrict__ ws) {
  __shared__ float xT[64*260];         // [w-col 0..63][row 0..255], pad 260
  __shared__ float L2[32*260];         // [16 ReKy + 16 ImKy][256 rows], pad 260
  __shared__ float cst[256], snt[256];
  const int t = threadIdx.x;
  const int img = blockIdx.x;

  cst[t] = ws[OF_COS + t];
  snt[t] = ws[OF_SIN + t];

  const int l8 = t & 7, r5 = t >> 3;   // staging: 16B-slot, row-group
  const int g  = t & 3, tr = t >> 2;   // compute: ky-group, row-quad
  const int ky0 = g * 4;

  __syncthreads();

  float cd[4], sd[4];                  // per-ky rotation step
#pragma unroll
  for (int kl = 0; kl < 4; ++kl) {
    cd[kl] = cst[ky0 + kl];
    sd[kl] = snt[ky0 + kl];
  }

  float ar[4][4], ai[4][4];            // [kl][row]
#pragma unroll
  for (int kl = 0; kl < 4; ++kl)
#pragma unroll
    for (int r = 0; r < 4; ++r) { ar[kl][r] = 0.f; ai[kl][r] = 0.f; }

  const float* xb = x + (size_t)img * 65536;
  float4 v[16];
#pragma unroll
  for (int jj = 0; jj < 8; ++jj) {
    const int row = r5 + 32*jj;
    v[jj]   = *(const float4*)(xb + row*256 + l8*4);
    v[8+jj] = *(const float4*)(xb + row*256 + 128 + l8*4);
  }

  for (int c = 0; c < 4; ++c) {
    __syncthreads();
#pragma unroll
    for (int jj = 0; jj < 8; ++jj) {
      const int row = r5 + 32*jj;
      xT[(l8*4+0)*260 + row] = v[jj].x;
      xT[(l8*4+1)*260 + row] = v[jj].y;
      xT[(l8*4+2)*260 + row] = v[jj].z;
      xT[(l8*4+3)*260 + row] = v[jj].w;
      xT[(32+l8*4+0)*260 + row] = v[8+jj].x;
      xT[(32+l8*4+1)*260 + row] = v[8+jj].y;
      xT[(32+l8*4+2)*260 + row] = v[8+jj].z;
      xT[(32+l8*4+3)*260 + row] = v[8+jj].w;
    }
    __syncthreads();
    if (c < 3) {                       // T14: issue next chunk loads now
      const int w0n = (c+1) * 32;
#pragma unroll
      for (int jj = 0; jj < 8; ++jj) {
        const int row = r5 + 32*jj;
        v[jj]   = *(const float4*)(xb + row*256 + w0n + l8*4);
        v[8+jj] = *(const float4*)(xb + row*256 + w0n + 128 + l8*4);
      }
    }
    float cc[4], sv[4];
#pragma unroll
    for (int kl = 0; kl < 4; ++kl) {
      const int m = ((ky0 + kl) * c * 32) & 255;
      cc[kl] = cst[m];
      sv[kl] = snt[m];
    }
#pragma unroll 8
    for (int wl = 0; wl < 32; ++wl) {
      const float4 xlo = *(const float4*)&xT[wl*260 + tr*4];
      const float4 xhi = *(const float4*)&xT[(wl+32)*260 + tr*4];
      const float xe0 = xlo.x + xhi.x, xo0 = xlo.x - xhi.x;
      const float xe1 = xlo.y + xhi.y, xo1 = xlo.y - xhi.y;
      const float xe2 = xlo.z + xhi.z, xo2 = xlo.z - xhi.z;
      const float xe3 = xlo.w + xhi.w, xo3 = xlo.w - xhi.w;
#pragma unroll
      for (int kl = 0; kl < 4; ++kl) {
        const float s0 = (kl & 1) ? xo0 : xe0;
        const float s1 = (kl & 1) ? xo1 : xe1;
        const float s2 = (kl & 1) ? xo2 : xe2;
        const float s3 = (kl & 1) ? xo3 : xe3;
        ar[kl][0] += s0 * cc[kl];  ai[kl][0] -= s0 * sv[kl];
        ar[kl][1] += s1 * cc[kl];  ai[kl][1] -= s1 * sv[kl];
        ar[kl][2] += s2 * cc[kl];  ai[kl][2] -= s2 * sv[kl];
        ar[kl][3] += s3 * cc[kl];  ai[kl][3] -= s3 * sv[kl];
        const float nc = cc[kl]*cd[kl] - sv[kl]*sd[kl];
        const float ns = sv[kl]*cd[kl] + cc[kl]*sd[kl];
        cc[kl] = nc; sv[kl] = ns;
      }
    }
  }

  // write Xw into L2 (LDS) instead of global
#pragma unroll
  for (int kl = 0; kl < 4; ++kl) {
    const int ky = ky0 + kl;
    float4 sr2; sr2.x = ar[kl][0]; sr2.y = ar[kl][1]; sr2.z = ar[kl][2]; sr2.w = ar[kl][3];
    float4 si2; si2.x = ai[kl][0]; si2.y = ai[kl][1]; si2.z = ai[kl][2]; si2.w = ai[kl][3];
    *(float4*)&L2[ky*260 + tr*4]      = sr2;
    *(float4*)&L2[(16+ky)*260 + tr*4] = si2;
  }
  __syncthreads();

  // ---- part 2: h-DFT ----
  const int kx = t >> 4, ky2 = t & 15;
  const float cdk = cst[kx], sdk = snt[kx];
  float c = 1.f, s = 0.f, arr = 0.f, aii = 0.f;
#pragma unroll 2
  for (int hq = 0; hq < 64; ++hq) {
    const float4 xr = *(const float4*)&L2[ky2*260 + hq*4];
    const float4 xi = *(const float4*)&L2[(16+ky2)*260 + hq*4];
    {
      arr += xr.x*c + xi.x*s;  aii += xi.x*c - xr.x*s;
      const float nc = c*cdk - s*sdk, ns = s*cdk + c*sdk; c = nc; s = ns;
    }
    {
      arr += xr.y*c + xi.y*s;  aii += xi.y*c - xr.y*s;
      const float nc = c*cdk - s*sdk, ns = s*cdk + c*sdk; c = nc; s = ns;
    }
    {
      arr += xr.z*c + xi.z*s;  aii += xi.z*c - xr.z*s;
      const float nc = c*cdk - s*sdk, ns = s*cdk + c*sdk; c = nc; s = ns;
    }
    {
      arr += xr.w*c + xi.w*s;  aii += xi.w*c - xr.w*s;
      const float nc = c*cdk - s*sdk, ns = s*cdk + c*sdk; c = nc; s = ns;
    }
  }
  ws[OF_XS_RE + img*256 + t] = arr;
  ws[OF_XS_IM + img*256 + t] = aii;
}

// Stage 3: o1/o2[b,o,m] = sum_i xs[b,i,m] * (wr + i wi)[i,o,m]
__global__ __launch_bounds__(256) void k3_mix(const float* __restrict__ w1r,
    const float* __restrict__ w1i, const float* __restrict__ w2r,
    const float* __restrict__ w2i, float* __restrict__ ws) {
  const int o  = blockIdx.x;     // 0..63
  const int mc = blockIdx.y;     // 0..3
  const int t  = threadIdx.x;    // 256
  const int b  = t >> 6;
  const int m  = (mc << 6) + (t & 63);
  const float* xsr = ws + OF_XS_RE;
  const float* xsi = ws + OF_XS_IM;
  float a1r=0.f, a1i=0.f, a2r=0.f, a2i=0.f;
#pragma unroll 4
  for (int i = 0; i < NCI; ++i) {
    const float xr = xsr[((b*NCI + i) << 8) + m];
    const float xi = xsi[((b*NCI + i) << 8) + m];
    const int wi = ((i*NCO + o) << 8) + m;
    const float p = w1r[wi], q = w1i[wi], u = w2r[wi], v = w2i[wi];
    a1r += xr*p - xi*q;
    a1i += xr*q + xi*p;
    a2r += xr*u - xi*v;
    a2i += xr*v + xi*u;
  }
  const int oi = ((b*NCO + o) << 8) + m;
  ws[OF_O1_RE + oi] = a1r;
  ws[OF_O1_IM + oi] = a1i;
  ws[OF_O2_RE + oi] = a2r;
  ws[OF_O2_IM + oi] = a2i;
}

// Fused stage 4+5.
// phase A: S[hl][ky] (complex, 64x16) into LDS; trig via dual rotation.
// phase B: radix-4 butterfly over ky mod 4 -> 4 columns per thread.
__global__ __launch_bounds__(256) void k45_idft(const float* __restrict__ ws,
                                                float* __restrict__ out) {
  __shared__ __align__(16) float o1r[256], o1i[256], o2r[256], o2i[256];
  __shared__ float cst[256], snt[256];
  __shared__ __align__(16) float Sr[64][20], Si[64][20];
  const int t  = threadIdx.x;
  const int bo = blockIdx.x >> 2;
  const int hc = blockIdx.x & 3;

  o1r[t] = ws[OF_O1_RE + bo*256 + t];
  o1i[t] = ws[OF_O1_IM + bo*256 + t];
  o2r[t] = ws[OF_O2_RE + bo*256 + t];
  o2i[t] = ws[OF_O2_IM + bo*256 + t];
  cst[t] = ws[OF_COS + t];
  snt[t] = ws[OF_SIN + t];

  const int w0 = t & 63;
  const float* Tw = ws + OF_TW;
  float c[15], s[15];
#pragma unroll
  for (int k = 0; k < 15; ++k) {
    c[k] = Tw[(2*k)*256 + w0];
    s[k] = Tw[(2*k+1)*256 + w0];
  }
  __syncthreads();

  // ---- phase A ----
  {
    const int hl = t >> 2, kq = t & 3;
    const int h  = hc*64 + hl;
    const float chh = cst[h], shh = snt[h];
    float c1 = 1.f, s1 = 0.f;
    const int m2i = (240 * h) & 255;
    float c2 = cst[m2i], s2 = snt[m2i];
    float4 sr = {0.f,0.f,0.f,0.f}, si = {0.f,0.f,0.f,0.f};
    for (int j = 0; j < 16; ++j) {
      const float4 r1 = *(const float4*)&o1r[j*16 + kq*4];
      const float4 i1 = *(const float4*)&o1i[j*16 + kq*4];
      const float4 r2 = *(const float4*)&o2r[j*16 + kq*4];
      const float4 i2 = *(const float4*)&o2i[j*16 + kq*4];
      sr.x += r1.x*c1 - i1.x*s1 + r2.x*c2 - i2.x*s2;
      si.x += r1.x*s1 + i1.x*c1 + r2.x*s2 + i2.x*c2;
      sr.y += r1.y*c1 - i1.y*s1 + r2.y*c2 - i2.y*s2;
      si.y += r1.y*s1 + i1.y*c1 + r2.y*s2 + i2.y*c2;
      sr.z += r1.z*c1 - i1.z*s1 + r2.z*c2 - i2.z*s2;
      si.z += r1.z*s1 + i1.z*c1 + r2.z*s2 + i2.z*c2;
      sr.w += r1.w*c1 - i1.w*s1 + r2.w*c2 - i2.w*s2;
      si.w += r1.w*s1 + i1.w*c1 + r2.w*s2 + i2.w*c2;
      const float n1c = c1*chh - s1*shh, n1s = s1*chh + c1*shh;
      const float n2c = c2*chh - s2*shh, n2s = s2*chh + c2*shh;
      c1 = n1c; s1 = n1s; c2 = n2c; s2 = n2s;
    }
    *(float4*)&Sr[hl][kq*4] = sr;
    *(float4*)&Si[hl][kq*4] = si;
  }
  __syncthreads();

  // ---- phase B: radix-4 butterfly over ky mod 4 ----
  const int rg = t >> 6;
  const float scale = 2.0f / 65536.0f;
  const size_t rowbase = ((size_t)bo*256 + hc*64 + rg*16) * 256;
#pragma unroll 2
  for (int r = 0; r < 16; ++r) {
    const int hl = rg*16 + r;
    const float4 a0 = *(const float4*)&Sr[hl][0];
    const float4 a1 = *(const float4*)&Sr[hl][4];
    const float4 a2 = *(const float4*)&Sr[hl][8];
    const float4 a3 = *(const float4*)&Sr[hl][12];
    const float4 b0 = *(const float4*)&Si[hl][0];
    const float4 b1 = *(const float4*)&Si[hl][4];
    const float4 b2 = *(const float4*)&Si[hl][8];
    const float4 b3 = *(const float4*)&Si[hl][12];

    float PA = 0.5f * a0.x;            // DC (ky=0), even class
    float PB = 0.f, PC = 0.f, PD = 0.f, QB = 0.f, QD = 0.f;
    // ky=1 (B)
    PB += a0.y*c[0] - b0.y*s[0];   QB += a0.y*s[0] + b0.y*c[0];
    // ky=2 (C)
    PC += a0.z*c[1] - b0.z*s[1];
    // ky=3 (D)
    PD += a0.w*c[2] - b0.w*s[2];   QD += a0.w*s[2] + b0.w*c[2];
    // ky=4 (A)
    PA += a1.x*c[3] - b1.x*s[3];
    // ky=5 (B)
    PB += a1.y*c[4] - b1.y*s[4];   QB += a1.y*s[4] + b1.y*c[4];
    // ky=6 (C)
    PC += a1.z*c[5] - b1.z*s[5];
    // ky=7 (D)
    PD += a1.w*c[6] - b1.w*s[6];   QD += a1.w*s[6] + b1.w*c[6];
    // ky=8 (A)
    PA += a2.x*c[7] - b2.x*s[7];
    // ky=9 (B)
    PB += a2.y*c[8] - b2.y*s[8];   QB += a2.y*s[8] + b2.y*c[8];
    // ky=10 (C)
    PC += a2.z*c[9] - b2.z*s[9];
    // ky=11 (D)
    PD += a2.w*c[10] - b2.w*s[10]; QD += a2.w*s[10] + b2.w*c[10];
    // ky=12 (A)
    PA += a3.x*c[11] - b3.x*s[11];
    // ky=13 (B)
    PB += a3.y*c[12] - b3.y*s[12]; QB += a3.y*s[12] + b3.y*c[12];
    // ky=14 (C)
    PC += a3.z*c[13] - b3.z*s[13];
    // ky=15 (D)
    PD += a3.w*c[14] - b3.w*s[14]; QD += a3.w*s[14] + b3.w*c[14];

    const float T1 = PA + PC, T2 = PB + PD;
    const float T3 = PA - PC, T4 = QB - QD;
    const size_t ob = rowbase + (size_t)r*256 + w0;
    out[ob]       = (T1 + T2) * scale;   // w0
    out[ob + 64]  = (T3 - T4) * scale;   // w0+64
    out[ob + 128] = (T1 - T2) * scale;   // w0+128
    out[ob + 192] = (T3 + T4) * scale;   // w0+192
  }
}

extern "C" void kernel_launch(void* const* d_in, const int* in_sizes, int n_in,
                              void* d_out, int out_size, void* d_ws, size_t ws_size,
                              hipStream_t stream) {
  const float* x   = (const float*)d_in[0];
  const float* w1r = (const float*)d_in[1];
  const float* w1i = (const float*)d_in[2];
  const float* w2r = (const float*)d_in[3];
  const float* w2i = (const float*)d_in[4];
  float* out = (float*)d_out;
  float* ws  = (float*)d_ws;

  hipLaunchKernelGGL(k0_init,  dim3(31),    dim3(256), 0, stream, ws);
  hipLaunchKernelGGL(k12_dft,  dim3(256),   dim3(256), 0, stream, x, ws);
  hipLaunchKernelGGL(k3_mix,   dim3(64, 4), dim3(256), 0, stream, w1r, w1i, w2r, w2i, ws);
  hipLaunchKernelGGL(k45_idft, dim3(1024),  dim3(256), 0, stream, ws, out);
}

// Round 7
// 68.953 us; speedup vs baseline: 3.5304x; 1.0268x over previous
//
#include <hip/hip_runtime.h>

#define NB 4
#define NCI 64
#define NCO 64
#define NH 256
#define NW 256
#define NIMG (NB*NCI)      // 256
#define PLANE (NIMG*NH)    // 65536

// workspace offsets (in floats)
#define OF_COS 0
#define OF_SIN 256
#define OF_TW  512                      // [30][256] final-stage trig (ky=1..15 cos/sin)
#define OF_XS_RE (16384 + 32*PLANE)
#define OF_XS_IM (OF_XS_RE + PLANE)
#define OF_O1_RE (OF_XS_IM + PLANE)
#define OF_O1_IM (OF_O1_RE + PLANE)
#define OF_O2_RE (OF_O1_IM + PLANE)
#define OF_O2_IM (OF_O2_RE + PLANE)

// grid 31: block 0 -> cos/sin tables; blocks 1..30 -> one TW row each
__global__ __launch_bounds__(256) void k0_init(float* __restrict__ ws) {
  const int t = threadIdx.x, b = blockIdx.x;
  const double TP = 6.283185307179586;
  if (b == 0) {
    double a = TP * t / 256.0;
    ws[OF_COS + t] = (float)cos(a);
    ws[OF_SIN + t] = (float)sin(a);
  } else {
    const int p = b - 1;              // 0..29
    const int ky = (p >> 1) + 1;
    double a = TP * ((ky * t) & 255) / 256.0;
    ws[OF_TW + p*256 + t] = (p & 1) ? (float)sin(a) : (float)cos(a);
  }
}

// Fused stage 1+2, 512 threads, grid 256 (1 img/block).
// part 1: w-DFT with (w,w+128) pre-fold at staging; 8 chunks x 16 lo-cols.
//   compute: thread = (wq=t&1, g=(t>>1)&3, tr=t>>3): 4 ky x 4 rows, half the
//   w-steps each; merged via __shfl_xor(.,1).
// part 2: h-DFT, hh = t>>8 halves of h, float2 scratch reduce.
// LDS: one 32x260 tile (chunk buffer, then Xw) + trig + 4KB scratch = 39.4 KB.
__global__ __launch_bounds__(512) void k12_dft(const float* __restrict__ x,
                                               float* __restrict__ ws) {
  __shared__ float buf[32*260];
  __shared__ float cst[256], snt[256];
  __shared__ float2 s2[512];
  const int t = threadIdx.x;
  const int img = blockIdx.x;

  if (t < 256) { cst[t] = ws[OF_COS + t]; snt[t] = ws[OF_SIN + t]; }

  const int sl = t & 3, rr = t >> 2;            // staging: 16B slot, row (rr, rr+128)
  const int wq = t & 1, g = (t >> 1) & 3, tr = t >> 3;  // compute map
  const int ky0 = g * 4;

  __syncthreads();

  float cd[4], sd[4];
#pragma unroll
  for (int kl = 0; kl < 4; ++kl) { cd[kl] = cst[ky0+kl]; sd[kl] = snt[ky0+kl]; }

  float ar[4][4], ai[4][4];
#pragma unroll
  for (int kl = 0; kl < 4; ++kl)
#pragma unroll
    for (int r = 0; r < 4; ++r) { ar[kl][r] = 0.f; ai[kl][r] = 0.f; }

  const float* xb = x + (size_t)img * 65536;
  float4 lo0 = *(const float4*)(xb + rr*256 + sl*4);
  float4 hi0 = *(const float4*)(xb + rr*256 + 128 + sl*4);
  float4 lo1 = *(const float4*)(xb + (rr+128)*256 + sl*4);
  float4 hi1 = *(const float4*)(xb + (rr+128)*256 + 128 + sl*4);

  for (int c = 0; c < 8; ++c) {
    __syncthreads();                  // prev chunk compute done
    buf[(sl*4+0)*260 + rr] = lo0.x + hi0.x;
    buf[(sl*4+1)*260 + rr] = lo0.y + hi0.y;
    buf[(sl*4+2)*260 + rr] = lo0.z + hi0.z;
    buf[(sl*4+3)*260 + rr] = lo0.w + hi0.w;
    buf[(16+sl*4+0)*260 + rr] = lo0.x - hi0.x;
    buf[(16+sl*4+1)*260 + rr] = lo0.y - hi0.y;
    buf[(16+sl*4+2)*260 + rr] = lo0.z - hi0.z;
    buf[(16+sl*4+3)*260 + rr] = lo0.w - hi0.w;
    buf[(sl*4+0)*260 + rr+128] = lo1.x + hi1.x;
    buf[(sl*4+1)*260 + rr+128] = lo1.y + hi1.y;
    buf[(sl*4+2)*260 + rr+128] = lo1.z + hi1.z;
    buf[(sl*4+3)*260 + rr+128] = lo1.w + hi1.w;
    buf[(16+sl*4+0)*260 + rr+128] = lo1.x - hi1.x;
    buf[(16+sl*4+1)*260 + rr+128] = lo1.y - hi1.y;
    buf[(16+sl*4+2)*260 + rr+128] = lo1.z - hi1.z;
    buf[(16+sl*4+3)*260 + rr+128] = lo1.w - hi1.w;
    __syncthreads();
    if (c < 7) {                      // T14: prefetch next chunk
      const int w0n = (c+1) * 16;
      lo0 = *(const float4*)(xb + rr*256 + w0n + sl*4);
      hi0 = *(const float4*)(xb + rr*256 + w0n + 128 + sl*4);
      lo1 = *(const float4*)(xb + (rr+128)*256 + w0n + sl*4);
      hi1 = *(const float4*)(xb + (rr+128)*256 + w0n + 128 + sl*4);
    }
    // rotation init at w0 = c*16 + wq*8
    float cc[4], sv[4];
#pragma unroll
    for (int kl = 0; kl < 4; ++kl) {
      const int m = ((ky0 + kl) * (c*16 + wq*8)) & 255;
      cc[kl] = cst[m];
      sv[kl] = snt[m];
    }
    const int wbase = wq * 8;
#pragma unroll
    for (int i = 0; i < 8; ++i) {
      const int wl = wbase + i;
      const float4 xe = *(const float4*)&buf[wl*260 + tr*4];
      const float4 xo = *(const float4*)&buf[(16+wl)*260 + tr*4];
#pragma unroll
      for (int kl = 0; kl < 4; ++kl) {
        const float s0 = (kl & 1) ? xo.x : xe.x;
        const float s1 = (kl & 1) ? xo.y : xe.y;
        const float s2v = (kl & 1) ? xo.z : xe.z;
        const float s3 = (kl & 1) ? xo.w : xe.w;
        ar[kl][0] += s0 * cc[kl];  ai[kl][0] -= s0 * sv[kl];
        ar[kl][1] += s1 * cc[kl];  ai[kl][1] -= s1 * sv[kl];
        ar[kl][2] += s2v * cc[kl]; ai[kl][2] -= s2v * sv[kl];
        ar[kl][3] += s3 * cc[kl];  ai[kl][3] -= s3 * sv[kl];
        const float nc = cc[kl]*cd[kl] - sv[kl]*sd[kl];
        const float ns = sv[kl]*cd[kl] + cc[kl]*sd[kl];
        cc[kl] = nc; sv[kl] = ns;
      }
    }
  }

  // merge the two w-halves (lane pairs)
#pragma unroll
  for (int kl = 0; kl < 4; ++kl)
#pragma unroll
    for (int r = 0; r < 4; ++r) {
      ar[kl][r] += __shfl_xor(ar[kl][r], 1);
      ai[kl][r] += __shfl_xor(ai[kl][r], 1);
    }
  __syncthreads();                    // all chunk reads done; safe to overwrite buf
  if (wq == 0) {
#pragma unroll
    for (int kl = 0; kl < 4; ++kl) {
      const int ky = ky0 + kl;
      float4 sr; sr.x = ar[kl][0]; sr.y = ar[kl][1]; sr.z = ar[kl][2]; sr.w = ar[kl][3];
      float4 si; si.x = ai[kl][0]; si.y = ai[kl][1]; si.z = ai[kl][2]; si.w = ai[kl][3];
      *(float4*)&buf[ky*260 + tr*4]      = sr;
      *(float4*)&buf[(16+ky)*260 + tr*4] = si;
    }
  }
  __syncthreads();

  // ---- part 2: h-DFT, h split across hh = t>>8 ----
  const int ky2 = t & 15, kx = (t >> 4) & 15, hh = t >> 8;
  const float cdk = cst[kx], sdk = snt[kx];
  float cR = (hh && (kx & 1)) ? -1.f : 1.f;   // cos(pi*kx) start for hh=1
  float sR = 0.f;
  float arr = 0.f, aii = 0.f;
  const int base = ky2*260 + hh*128;
#pragma unroll 4
  for (int hq = 0; hq < 32; ++hq) {
    const float4 xr = *(const float4*)&buf[base + hq*4];
    const float4 xi = *(const float4*)&buf[16*260 + base + hq*4];
    {
      arr += xr.x*cR + xi.x*sR;  aii += xi.x*cR - xr.x*sR;
      const float nc = cR*cdk - sR*sdk, ns = sR*cdk + cR*sdk; cR = nc; sR = ns;
    }
    {
      arr += xr.y*cR + xi.y*sR;  aii += xi.y*cR - xr.y*sR;
      const float nc = cR*cdk - sR*sdk, ns = sR*cdk + cR*sdk; cR = nc; sR = ns;
    }
    {
      arr += xr.z*cR + xi.z*sR;  aii += xi.z*cR - xr.z*sR;
      const float nc = cR*cdk - sR*sdk, ns = sR*cdk + cR*sdk; cR = nc; sR = ns;
    }
    {
      arr += xr.w*cR + xi.w*sR;  aii += xi.w*cR - xr.w*sR;
      const float nc = cR*cdk - sR*sdk, ns = sR*cdk + cR*sdk; cR = nc; sR = ns;
    }
  }
  s2[t].x = arr; s2[t].y = aii;
  __syncthreads();
  if (t < 256) {
    const float2 a = s2[t], b2 = s2[t + 256];
    ws[OF_XS_RE + img*256 + t] = a.x + b2.x;
    ws[OF_XS_IM + img*256 + t] = a.y + b2.y;
  }
}

// Stage 3: o1/o2[b,o,m] = sum_i xs[b,i,m] * (wr + i wi)[i,o,m]
__global__ __launch_bounds__(256) void k3_mix(const float* __restrict__ w1r,
    const float* __restrict__ w1i, const float* __restrict__ w2r,
    const float* __restrict__ w2i, float* __restrict__ ws) {
  const int o  = blockIdx.x;     // 0..63
  const int mc = blockIdx.y;     // 0..3
  const int t  = threadIdx.x;    // 256
  const int b  = t >> 6;
  const int m  = (mc << 6) + (t & 63);
  const float* xsr = ws + OF_XS_RE;
  const float* xsi = ws + OF_XS_IM;
  float a1r=0.f, a1i=0.f, a2r=0.f, a2i=0.f;
#pragma unroll 4
  for (int i = 0; i < NCI; ++i) {
    const float xr = xsr[((b*NCI + i) << 8) + m];
    const float xi = xsi[((b*NCI + i) << 8) + m];
    const int wi = ((i*NCO + o) << 8) + m;
    const float p = w1r[wi], q = w1i[wi], u = w2r[wi], v = w2i[wi];
    a1r += xr*p - xi*q;
    a1i += xr*q + xi*p;
    a2r += xr*u - xi*v;
    a2i += xr*v + xi*u;
  }
  const int oi = ((b*NCO + o) << 8) + m;
  ws[OF_O1_RE + oi] = a1r;
  ws[OF_O1_IM + oi] = a1i;
  ws[OF_O2_RE + oi] = a2r;
  ws[OF_O2_IM + oi] = a2i;
}

// Fused stage 4+5.
// phase A: S[hl][ky] (complex, 64x16) into LDS; trig via dual rotation.
// phase B: radix-4 butterfly over ky mod 4 -> 4 columns per thread.
__global__ __launch_bounds__(256) void k45_idft(const float* __restrict__ ws,
                                                float* __restrict__ out) {
  __shared__ __align__(16) float o1r[256], o1i[256], o2r[256], o2i[256];
  __shared__ float cst[256], snt[256];
  __shared__ __align__(16) float Sr[64][20], Si[64][20];
  const int t  = threadIdx.x;
  const int bo = blockIdx.x >> 2;
  const int hc = blockIdx.x & 3;

  o1r[t] = ws[OF_O1_RE + bo*256 + t];
  o1i[t] = ws[OF_O1_IM + bo*256 + t];
  o2r[t] = ws[OF_O2_RE + bo*256 + t];
  o2i[t] = ws[OF_O2_IM + bo*256 + t];
  cst[t] = ws[OF_COS + t];
  snt[t] = ws[OF_SIN + t];

  const int w0 = t & 63;
  const float* Tw = ws + OF_TW;
  float c[15], s[15];
#pragma unroll
  for (int k = 0; k < 15; ++k) {
    c[k] = Tw[(2*k)*256 + w0];
    s[k] = Tw[(2*k+1)*256 + w0];
  }
  __syncthreads();

  // ---- phase A ----
  {
    const int hl = t >> 2, kq = t & 3;
    const int h  = hc*64 + hl;
    const float chh = cst[h], shh = snt[h];
    float c1 = 1.f, s1 = 0.f;
    const int m2i = (240 * h) & 255;
    float c2 = cst[m2i], s2 = snt[m2i];
    float4 sr = {0.f,0.f,0.f,0.f}, si = {0.f,0.f,0.f,0.f};
    for (int j = 0; j < 16; ++j) {
      const float4 r1 = *(const float4*)&o1r[j*16 + kq*4];
      const float4 i1 = *(const float4*)&o1i[j*16 + kq*4];
      const float4 r2 = *(const float4*)&o2r[j*16 + kq*4];
      const float4 i2 = *(const float4*)&o2i[j*16 + kq*4];
      sr.x += r1.x*c1 - i1.x*s1 + r2.x*c2 - i2.x*s2;
      si.x += r1.x*s1 + i1.x*c1 + r2.x*s2 + i2.x*c2;
      sr.y += r1.y*c1 - i1.y*s1 + r2.y*c2 - i2.y*s2;
      si.y += r1.y*s1 + i1.y*c1 + r2.y*s2 + i2.y*c2;
      sr.z += r1.z*c1 - i1.z*s1 + r2.z*c2 - i2.z*s2;
      si.z += r1.z*s1 + i1.z*c1 + r2.z*s2 + i2.z*c2;
      sr.w += r1.w*c1 - i1.w*s1 + r2.w*c2 - i2.w*s2;
      si.w += r1.w*s1 + i1.w*c1 + r2.w*s2 + i2.w*c2;
      const float n1c = c1*chh - s1*shh, n1s = s1*chh + c1*shh;
      const float n2c = c2*chh - s2*shh, n2s = s2*chh + c2*shh;
      c1 = n1c; s1 = n1s; c2 = n2c; s2 = n2s;
    }
    *(float4*)&Sr[hl][kq*4] = sr;
    *(float4*)&Si[hl][kq*4] = si;
  }
  __syncthreads();

  // ---- phase B: radix-4 butterfly over ky mod 4 ----
  const int rg = t >> 6;
  const float scale = 2.0f / 65536.0f;
  const size_t rowbase = ((size_t)bo*256 + hc*64 + rg*16) * 256;
#pragma unroll 2
  for (int r = 0; r < 16; ++r) {
    const int hl = rg*16 + r;
    const float4 a0 = *(const float4*)&Sr[hl][0];
    const float4 a1 = *(const float4*)&Sr[hl][4];
    const float4 a2 = *(const float4*)&Sr[hl][8];
    const float4 a3 = *(const float4*)&Sr[hl][12];
    const float4 b0 = *(const float4*)&Si[hl][0];
    const float4 b1 = *(const float4*)&Si[hl][4];
    const float4 b2 = *(const float4*)&Si[hl][8];
    const float4 b3 = *(const float4*)&Si[hl][12];

    float PA = 0.5f * a0.x;
    float PB = 0.f, PC = 0.f, PD = 0.f, QB = 0.f, QD = 0.f;
    PB += a0.y*c[0] - b0.y*s[0];   QB += a0.y*s[0] + b0.y*c[0];
    PC += a0.z*c[1] - b0.z*s[1];
    PD += a0.w*c[2] - b0.w*s[2];   QD += a0.w*s[2] + b0.w*c[2];
    PA += a1.x*c[3] - b1.x*s[3];
    PB += a1.y*c[4] - b1.y*s[4];   QB += a1.y*s[4] + b1.y*c[4];
    PC += a1.z*c[5] - b1.z*s[5];
    PD += a1.w*c[6] - b1.w*s[6];   QD += a1.w*s[6] + b1.w*c[6];
    PA += a2.x*c[7] - b2.x*s[7];
    PB += a2.y*c[8] - b2.y*s[8];   QB += a2.y*s[8] + b2.y*c[8];
    PC += a2.z*c[9] - b2.z*s[9];
    PD += a2.w*c[10] - b2.w*s[10]; QD += a2.w*s[10] + b2.w*c[10];
    PA += a3.x*c[11] - b3.x*s[11];
    PB += a3.y*c[12] - b3.y*s[12]; QB += a3.y*s[12] + b3.y*c[12];
    PC += a3.z*c[13] - b3.z*s[13];
    PD += a3.w*c[14] - b3.w*s[14]; QD += a3.w*s[14] + b3.w*c[14];

    const float T1 = PA + PC, T2 = PB + PD;
    const float T3 = PA - PC, T4 = QB - QD;
    const size_t ob = rowbase + (size_t)r*256 + w0;
    out[ob]       = (T1 + T2) * scale;
    out[ob + 64]  = (T3 - T4) * scale;
    out[ob + 128] = (T1 - T2) * scale;
    out[ob + 192] = (T3 + T4) * scale;
  }
}

extern "C" void kernel_launch(void* const* d_in, const int* in_sizes, int n_in,
                              void* d_out, int out_size, void* d_ws, size_t ws_size,
                              hipStream_t stream) {
  const float* x   = (const float*)d_in[0];
  const float* w1r = (const float*)d_in[1];
  const float* w1i = (const float*)d_in[2];
  const float* w2r = (const float*)d_in[3];
  const float* w2i = (const float*)d_in[4];
  float* out = (float*)d_out;
  float* ws  = (float*)d_ws;

  hipLaunchKernelGGL(k0_init,  dim3(31),    dim3(256), 0, stream, ws);
  hipLaunchKernelGGL(k12_dft,  dim3(256),   dim3(512), 0, stream, x, ws);
  hipLaunchKernelGGL(k3_mix,   dim3(64, 4), dim3(256), 0, stream, w1r, w1i, w2r, w2i, ws);
  hipLaunchKernelGGL(k45_idft, dim3(1024),  dim3(256), 0, stream, ws, out);
}